// Round 4
// baseline (653.763 us; speedup 1.0000x reference)
//
#include <hip/hip_runtime.h>
#include <hip/hip_bf16.h>

typedef __hip_bfloat16 bf16;

#define B_ 2
#define T_ 1024
#define C_ 1024
#define H_ 16
#define N_ 64

using short8 = __attribute__((ext_vector_type(8))) short;
using f32x4 = __attribute__((ext_vector_type(4))) float;

__device__ __forceinline__ float us2f(unsigned short u) {
  return __uint_as_float(((unsigned int)u) << 16);
}
__device__ __forceinline__ float bs2f(short s) {
  return __uint_as_float(((unsigned int)(unsigned short)s) << 16);
}
__device__ __forceinline__ bf16 f2bf(float f) { return __float2bfloat16(f); }
__device__ __forceinline__ float sigmoidf_(float x) { return 1.0f / (1.0f + expf(-x)); }
__device__ __forceinline__ float softplusf_(float x) {
  return fmaxf(x, 0.0f) + log1pf(expf(-fabsf(x)));
}
// Full 16-lane-row sum, all lanes receive the result. Pure-VALU DPP:
// quad_perm xor1, xor2 give quad sums; row_ror:4 + row_ror:8 complete it.
__device__ __forceinline__ float qsum16(float x) {
  int a = __builtin_amdgcn_update_dpp(0, __float_as_int(x), 0xB1, 0xF, 0xF, true);
  x += __int_as_float(a);                       // quad_perm [1,0,3,2] (xor 1)
  int b = __builtin_amdgcn_update_dpp(0, __float_as_int(x), 0x4E, 0xF, 0xF, true);
  x += __int_as_float(b);                       // quad_perm [2,3,0,1] (xor 2)
  int c = __builtin_amdgcn_update_dpp(0, __float_as_int(x), 0x124, 0xF, 0xF, true);
  x += __int_as_float(c);                       // row_ror:4
  int d = __builtin_amdgcn_update_dpp(0, __float_as_int(x), 0x128, 0xF, 0xF, true);
  x += __int_as_float(d);                       // row_ror:8
  return x;
}

// ---------------- K0: fused weight fp32->bf16 conversion (big weights) ------
__global__ __launch_bounds__(256) void cvt_weights_kernel(
    const float* __restrict__ s0, const float* __restrict__ s1,
    const float* __restrict__ s2, const float* __restrict__ s3,
    const float* __restrict__ s4, const float* __restrict__ s5,
    const float* __restrict__ s6,
    bf16* __restrict__ d0, bf16* __restrict__ d1, bf16* __restrict__ d2,
    bf16* __restrict__ d3, bf16* __restrict__ d4, bf16* __restrict__ d5,
    bf16* __restrict__ d6) {
  long i4 = (long)blockIdx.x * 256 + threadIdx.x;
  const float* s; bf16* d; long off;
  if (i4 < 32768) { s = s0; d = d0; off = i4; }
  else if (i4 < 294912) { s = s1; d = d1; off = i4 - 32768; }
  else if (i4 < 327680) { s = s2; d = d2; off = i4 - 294912; }
  else if (i4 < 360448) { s = s3; d = d3; off = i4 - 327680; }
  else if (i4 < 622592) { s = s4; d = d4; off = i4 - 360448; }
  else if (i4 < 884736) { s = s5; d = d5; off = i4 - 622592; }
  else { s = s6; d = d6; off = i4 - 884736; }
  float4 v = *(const float4*)(s + off * 4);
  d[off * 4 + 0] = f2bf(v.x);
  d[off * 4 + 1] = f2bf(v.y);
  d[off * 4 + 2] = f2bf(v.z);
  d[off * 4 + 3] = f2bf(v.w);
}

// ---------------- K0b: pack small LoRA-1 weights to bf16 --------------------
__global__ __launch_bounds__(256) void cvt_small_kernel(
    const float* __restrict__ tkw1, const float* __restrict__ mkw1,
    const float* __restrict__ tdw1, const float* __restrict__ taw1,
    const float* __restrict__ maw1,
    bf16* __restrict__ wsk, bf16* __restrict__ wswa) {
  long i4 = (long)blockIdx.x * 256 + threadIdx.x;  // < 32768
  const float* s; bf16* d; long so, dof;
  if (i4 < 4096) { s = tkw1; so = i4; d = wsk; dof = i4; }
  else if (i4 < 8192) { s = mkw1; so = i4 - 4096; d = wsk; dof = i4; }
  else if (i4 < 24576) { s = tdw1; so = i4 - 8192; d = wswa; dof = i4 - 8192; }
  else if (i4 < 28672) { s = taw1; so = i4 - 24576; d = wswa; dof = i4 - 8192; }
  else { s = maw1; so = i4 - 28672; d = wswa; dof = i4 - 8192; }
  float4 v = *(const float4*)(s + so * 4);
  d[dof * 4 + 0] = f2bf(v.x);
  d[dof * 4 + 1] = f2bf(v.y);
  d[dof * 4 + 2] = f2bf(v.z);
  d[dof * 4 + 3] = f2bf(v.w);
}

// ---------------- K0c: LoRA-2 weights to bf16 -------------------------------
__global__ __launch_bounds__(256) void cvt_small2_kernel(
    const float* __restrict__ tmw2, const float* __restrict__ tdw2,
    const float* __restrict__ tkw2, const float* __restrict__ taw2,
    const float* __restrict__ maw2, const float* __restrict__ mkw2,
    bf16* __restrict__ tmw2b, bf16* __restrict__ tdw2b,
    bf16* __restrict__ tkw2b, bf16* __restrict__ taw2b,
    bf16* __restrict__ maw2b, bf16* __restrict__ mkw2b) {
  long i4 = (long)blockIdx.x * 256 + threadIdx.x;  // < 65536
  const float* s; bf16* d; long off;
  if (i4 < 32768) { s = tmw2; d = tmw2b; off = i4; }
  else if (i4 < 49152) { s = tdw2; d = tdw2b; off = i4 - 32768; }
  else if (i4 < 53248) { s = tkw2; d = tkw2b; off = i4 - 49152; }
  else if (i4 < 57344) { s = taw2; d = taw2b; off = i4 - 53248; }
  else if (i4 < 61440) { s = maw2; d = maw2b; off = i4 - 57344; }
  else { s = mkw2; d = mkw2b; off = i4 - 61440; }
  float4 v = *(const float4*)(s + off * 4);
  d[off * 4 + 0] = f2bf(v.x);
  d[off * 4 + 1] = f2bf(v.y);
  d[off * 4 + 2] = f2bf(v.z);
  d[off * 4 + 3] = f2bf(v.w);
}

// ---------------- K1: token shift (writes xx f32, xxx bf16) -----------------
__global__ __launch_bounds__(256) void shift_kernel(
    const float* __restrict__ x, const float* __restrict__ tmx,
    float* __restrict__ xx, bf16* __restrict__ xxxb) {
  long idx = (long)blockIdx.x * 256 + threadIdx.x;  // < B*T*C
  int c = (int)(idx & (C_ - 1));
  int t = (int)((idx >> 10) & (T_ - 1));
  float xv = x[idx];
  float xp = (t > 0) ? x[idx - C_] : 0.0f;
  float d = xp - xv;
  xx[idx] = d;
  xxxb[idx] = f2bf(xv + d * tmx[c]);
}

// ---------------- MFMA GEMM: C = A(bf16 MxK) * W^T (W bf16 NxK) -------------
__global__ __launch_bounds__(256) void gemm_mfma_kernel(
    const bf16* __restrict__ A, const bf16* __restrict__ W,
    float* __restrict__ Cf, bf16* __restrict__ Cb,
    int M, int N, int K, int actN) {
  __shared__ __align__(16) bf16 As[64][72];  // 144B row stride, 16B aligned
  __shared__ __align__(16) bf16 Ws[64][72];
  int tid = threadIdx.x;
  int m0 = blockIdx.y << 6, n0 = blockIdx.x << 6;
  int srow = tid >> 2, skg = (tid & 3) << 4;   // staging: row, 16 bf16 per thread
  int wv = tid >> 6, lane = tid & 63;
  int fr = lane & 15, fq = lane >> 4;
  f32x4 acc0 = {0.f, 0.f, 0.f, 0.f}, acc1 = acc0, acc2 = acc0, acc3 = acc0;
  bool wok = (n0 + srow) < N;
  const bf16* Ap = A + (long)(m0 + srow) * K + skg;
  const bf16* Wp = W + (long)(n0 + srow) * K + skg;
  short8 zz = {0, 0, 0, 0, 0, 0, 0, 0};
  for (int k0 = 0; k0 < K; k0 += 64) {
    *(short8*)&As[srow][skg] = *(const short8*)(Ap + k0);
    *(short8*)&As[srow][skg + 8] = *(const short8*)(Ap + k0 + 8);
    *(short8*)&Ws[srow][skg] = wok ? *(const short8*)(Wp + k0) : zz;
    *(short8*)&Ws[srow][skg + 8] = wok ? *(const short8*)(Wp + k0 + 8) : zz;
    __syncthreads();
#pragma unroll
    for (int kk = 0; kk < 2; kk++) {
      int ko = (fq << 3) + (kk << 5);
      short8 af = *(const short8*)&As[(wv << 4) + fr][ko];
      short8 b0 = *(const short8*)&Ws[fr][ko];
      short8 b1 = *(const short8*)&Ws[16 + fr][ko];
      short8 b2 = *(const short8*)&Ws[32 + fr][ko];
      short8 b3 = *(const short8*)&Ws[48 + fr][ko];
      acc0 = __builtin_amdgcn_mfma_f32_16x16x32_bf16(af, b0, acc0, 0, 0, 0);
      acc1 = __builtin_amdgcn_mfma_f32_16x16x32_bf16(af, b1, acc1, 0, 0, 0);
      acc2 = __builtin_amdgcn_mfma_f32_16x16x32_bf16(af, b2, acc2, 0, 0, 0);
      acc3 = __builtin_amdgcn_mfma_f32_16x16x32_bf16(af, b3, acc3, 0, 0, 0);
    }
    __syncthreads();
  }
  int orow = m0 + (wv << 4) + (fq << 2);
  int ocol = n0 + fr;
  f32x4 av[4] = {acc0, acc1, acc2, acc3};
#pragma unroll
  for (int nt = 0; nt < 4; nt++) {
    int col = ocol + (nt << 4);
    if (col < N) {
#pragma unroll
      for (int r = 0; r < 4; r++) {
        float vvv = av[nt][r];
        if (col < actN) vvv = tanhf(vvv);
        long oi = (long)(orow + r) * N + col;
        if (Cb) Cb[oi] = f2bf(vvv); else Cf[oi] = vvv;
      }
    }
  }
}

// ---------------- K3: deltas + build xrg/xwa/xk/xv (bf16 out) ---------------
__global__ __launch_bounds__(256) void mix4_kernel(
    const float* __restrict__ x, const float* __restrict__ xx,
    const float* __restrict__ mix, const float* __restrict__ tmaa,
    const bf16* __restrict__ w2b,
    bf16* __restrict__ xrg, bf16* __restrict__ xwa,
    bf16* __restrict__ xk, bf16* __restrict__ xv) {
  int m = blockIdx.x;
  int tid = threadIdx.x;
  __shared__ float mrow[128];
  if (tid < 128) mrow[tid] = mix[(long)m * 128 + tid];
  __syncthreads();
#pragma unroll
  for (int cc = 0; cc < 4; cc++) {
    int c = tid + (cc << 8);
    long off = (long)m * C_ + c;
    float xb = x[off];
    float xxv = xx[off];
    float res[4];
#pragma unroll
    for (int f = 0; f < 4; f++) {
      const short8* wp = (const short8*)(w2b + (((long)f * C_ + c) << 5));
      float dl = 0.f;
#pragma unroll
      for (int d8 = 0; d8 < 4; d8++) {
        short8 u = wp[d8];
        int db = (f << 5) + (d8 << 3);
#pragma unroll
        for (int e = 0; e < 8; e++) dl += mrow[db + e] * bs2f(u[e]);
      }
      res[f] = xb + xxv * (tmaa[f * C_ + c] + dl);
    }
    xrg[off] = f2bf(res[0]); xwa[off] = f2bf(res[1]);
    xk[off] = f2bf(res[2]); xv[off] = f2bf(res[3]);
  }
}

// ---------------- K5: stage-2 small GEMMs + gates + per-head kk norm --------
__global__ __launch_bounds__(256) void fuse2_kernel(
    const float* __restrict__ kraw, const float* __restrict__ out1,
    const float* __restrict__ out2,
    const bf16* __restrict__ dw2, const bf16* __restrict__ kkw2,
    const bf16* __restrict__ aw2, const bf16* __restrict__ maw2,
    const bf16* __restrict__ mkw2,
    const float* __restrict__ tdec, const float* __restrict__ taa,
    const float* __restrict__ tma, const float* __restrict__ tmk,
    float* __restrict__ ew, float* __restrict__ kfin,
    float* __restrict__ kkn, float* __restrict__ bbo) {
  int m = blockIdx.x, tid = threadIdx.x;
  __shared__ float w1r[64], kk1r[16], a1r[16], ma1r[16], mk1r[16];
  if (tid < 64) w1r[tid] = out2[(long)m * 96 + tid];
  else if (tid < 80) kk1r[tid - 64] = out1[(long)m * 32 + (tid - 64)];
  else if (tid < 96) a1r[tid - 80] = out2[(long)m * 96 + 64 + (tid - 80)];
  else if (tid < 112) ma1r[tid - 96] = out2[(long)m * 96 + 80 + (tid - 96)];
  else if (tid < 128) mk1r[tid - 112] = out1[(long)m * 32 + 16 + (tid - 112)];
  __syncthreads();
  float kkp[4], av[4], wv[4], kr[4], mkv[4];
  float sumsq = 0.f;
#pragma unroll
  for (int j = 0; j < 4; j++) {
    int c = (tid << 2) + j;
    long off = (long)m * C_ + c;
    float wd = 0.f;
    const short8* dp = (const short8*)(dw2 + ((long)c << 6));
#pragma unroll
    for (int d8 = 0; d8 < 8; d8++) {
      short8 u = dp[d8];
      int db = d8 << 3;
#pragma unroll
      for (int e = 0; e < 8; e++) wd += w1r[db + e] * bs2f(u[e]);
    }
    float w = -softplusf_(-(tdec[c] + wd)) - 0.5f;
    wv[j] = w;
    float kd = 0.f, ad = 0.f, mad = 0.f, mkd = 0.f;
    const short8* kp = (const short8*)(kkw2 + ((long)c << 4));
    const short8* ap = (const short8*)(aw2 + ((long)c << 4));
    const short8* mp = (const short8*)(maw2 + ((long)c << 4));
    const short8* qp = (const short8*)(mkw2 + ((long)c << 4));
#pragma unroll
    for (int d8 = 0; d8 < 2; d8++) {
      short8 u1 = kp[d8], u2 = ap[d8], u3 = mp[d8], u4 = qp[d8];
      int db = d8 << 3;
#pragma unroll
      for (int e = 0; e < 8; e++) {
        kd += kk1r[db + e] * bs2f(u1[e]);
        ad += a1r[db + e] * bs2f(u2[e]);
        mad += ma1r[db + e] * bs2f(u3[e]);
        mkd += mk1r[db + e] * bs2f(u4[e]);
      }
    }
    float krw = kraw[off];
    float kkpre = krw + kd;
    kkp[j] = kkpre;
    sumsq += kkpre * kkpre;
    float a = sigmoidf_(taa[c] + ad);
    av[j] = a;
    float ma = sigmoidf_(tma[c] + mad);
    float mk = sigmoidf_(tmk[c] + mkd);
    mkv[j] = mk;
    kr[j] = krw * (ma + a * (1.f - ma));
  }
  sumsq += __shfl_xor(sumsq, 1);
  sumsq += __shfl_xor(sumsq, 2);
  sumsq += __shfl_xor(sumsq, 4);
  sumsq += __shfl_xor(sumsq, 8);
  float rn = 1.0f / fmaxf(sqrtf(sumsq), 1e-12f);
#pragma unroll
  for (int j = 0; j < 4; j++) {
    int c = (tid << 2) + j;
    long off = (long)m * C_ + c;
    float kknv = kkp[j] * rn;
    kkn[off] = kknv;
    bbo[off] = -kknv * av[j];
    ew[off] = expf(wv[j]);
    kfin[off] = kr[j] * expf(wv[j] * mkv[j]);
  }
}

// ---------------- K6: RWKV-7 scan, 256 blocks x 128 threads -----------------
// Rows of the 64x64 state are independent (sab and y are per-row reductions
// over keys), so the 2048 (b,h,row) rows spread freely. Total wave count is
// fixed at 512 (4 rows x 16 q-lanes per wave); the free variable is PACKING.
// R3 measured 314 cyc/token with 4 waves/block on 128 CUs and was invariant
// under scheduling changes -> LDS-pipe throughput floor (24 ds_read/token on
// each of 128 busy LDS pipes; 5xb128+1xb32 per wave ~ 280 cyc/token). R4:
// 256 blocks x 2 waves = 1 block per CU on ALL 256 CUs -> 12 ds_read/token
// per LDS pipe, halving the floor. Cost: 8 blocks/(b,h) re-read the streams;
// bid = rg*32 + bh makes bid%8 = bh%8 so the 8 rowgroup-blocks of one (b,h)
// land on the SAME XCD (round-robin dispatch) and share its L2 (1.5MB/bh,
// temporally aligned) -- HBM fetch stays ~flat. Double-buffered LDS, 3-set
// rotating register pipeline, sched_barrier(0x7) kept from R3.
#define SCHUNK 16
#define NCHUNK (T_ / SCHUNK)
__global__ __launch_bounds__(128, 1) void scan_kernel(
    const float* __restrict__ rB, const float* __restrict__ ewB,
    const float* __restrict__ kB, const float* __restrict__ vB,
    const float* __restrict__ kkB, const float* __restrict__ bbB,
    float* __restrict__ yB) {
  __shared__ __align__(16) float lds[2][6][SCHUNK * 64];
  int bid = blockIdx.x;          // 0..255 : bid = rg*32 + bh
  int rg = bid >> 5, bh = bid & 31;
  int b = bh >> 4, h = bh & 15;
  int tid = threadIdx.x;         // 0..127
  int wave = tid >> 6, lane = tid & 63;
  int g = lane >> 4, q = lane & 15;
  int row = (rg << 3) + (wave << 2) + g;   // this lane's single row (0..63)
  int kq = q << 2;                         // 4 keys: kq..kq+3
  const long base = ((long)b * T_) * C_ + (h << 6);
  const float* s0 = kkB + base;
  const float* s1 = ewB + base;
  const float* s2 = kB + base;
  const float* s3 = bbB + base;
  const float* s4 = rB + base;
  const float* s5 = vB + base;
  int stok = tid >> 3;           // staging token within chunk (0..15)
  int spc = (tid & 7) << 3;      // float offset within token row (0,8,..,56)
  int lo = (stok << 6) + spc;    // LDS float offset
  // 12 staging registers (2 float4 per stream per thread)
  float4 r0a, r0b, r1a, r1b, r2a, r2b, r3a, r3b, r4a, r4b, r5a, r5b;
  auto loadc = [&](int c) {
    long go = (long)((c << 4) + stok) * C_ + spc;
    r0a = *(const float4*)(s0 + go); r0b = *(const float4*)(s0 + go + 4);
    r1a = *(const float4*)(s1 + go); r1b = *(const float4*)(s1 + go + 4);
    r2a = *(const float4*)(s2 + go); r2b = *(const float4*)(s2 + go + 4);
    r3a = *(const float4*)(s3 + go); r3b = *(const float4*)(s3 + go + 4);
    r4a = *(const float4*)(s4 + go); r4b = *(const float4*)(s4 + go + 4);
    r5a = *(const float4*)(s5 + go); r5b = *(const float4*)(s5 + go + 4);
  };
  auto stage = [&](int buf) {
    *(float4*)&lds[buf][0][lo] = r0a; *(float4*)&lds[buf][0][lo + 4] = r0b;
    *(float4*)&lds[buf][1][lo] = r1a; *(float4*)&lds[buf][1][lo + 4] = r1b;
    *(float4*)&lds[buf][2][lo] = r2a; *(float4*)&lds[buf][2][lo + 4] = r2b;
    *(float4*)&lds[buf][3][lo] = r3a; *(float4*)&lds[buf][3][lo + 4] = r3b;
    *(float4*)&lds[buf][4][lo] = r4a; *(float4*)&lds[buf][4][lo + 4] = r4b;
    *(float4*)&lds[buf][5][lo] = r5a; *(float4*)&lds[buf][5][lo + 4] = r5b;
  };
  float S0 = 0.f, S1 = 0.f, S2 = 0.f, S3 = 0.f;
  // 3 rotating prefetch sets (static names; token tt uses set tt%3)
  float4 Q0kk, Q0ew, Q0k, Q0bb, Q0r; float Q0v;
  float4 Q1kk, Q1ew, Q1k, Q1bb, Q1r; float Q1v;
  float4 Q2kk, Q2ew, Q2k, Q2bb, Q2r; float Q2v;

#define PF(i, tt) { int tb_ = ((tt) << 6); \
    Q##i##kk = *(const float4*)&lds[cur][0][tb_ + kq]; \
    Q##i##ew = *(const float4*)&lds[cur][1][tb_ + kq]; \
    Q##i##k  = *(const float4*)&lds[cur][2][tb_ + kq]; \
    Q##i##bb = *(const float4*)&lds[cur][3][tb_ + kq]; \
    Q##i##r  = *(const float4*)&lds[cur][4][tb_ + kq]; \
    Q##i##v  = lds[cur][5][tb_ + row]; }
#define SBAR __builtin_amdgcn_sched_barrier(0x7)
#define ST(i, gtok) { \
    float p_ = fmaf(S1, Q##i##kk.y, S0 * Q##i##kk.x) + \
               fmaf(S3, Q##i##kk.w, S2 * Q##i##kk.z); \
    float sab = qsum16(p_); \
    float n0 = fmaf(S0, Q##i##ew.x, Q##i##v * Q##i##k.x); \
    float n1 = fmaf(S1, Q##i##ew.y, Q##i##v * Q##i##k.y); \
    float n2 = fmaf(S2, Q##i##ew.z, Q##i##v * Q##i##k.z); \
    float n3 = fmaf(S3, Q##i##ew.w, Q##i##v * Q##i##k.w); \
    S0 = fmaf(sab, Q##i##bb.x, n0); \
    S1 = fmaf(sab, Q##i##bb.y, n1); \
    S2 = fmaf(sab, Q##i##bb.z, n2); \
    S3 = fmaf(sab, Q##i##bb.w, n3); \
    float yp_ = fmaf(S1, Q##i##r.y, S0 * Q##i##r.x) + \
                fmaf(S3, Q##i##r.w, S2 * Q##i##r.z); \
    float yv_ = qsum16(yp_); \
    if (q == 0) yB[base + (long)(gtok) * C_ + row] = yv_; }

  // prologue: chunk 0 -> buf0; chunk 1 loaded into regs
  loadc(0);
  stage(0);
  loadc(1);
  __syncthreads();
  int cur = 0;
  for (int c = 0; c < NCHUNK; c++) {
    int t0 = c << 4;
    // prefetch tokens 0,1 of this chunk (reads queue before the stage writes)
    PF(0, 0); PF(1, 1);
    if (c + 1 < NCHUNK) stage(cur ^ 1);   // regs hold chunk c+1
    if (c + 2 < NCHUNK) loadc(c + 2);     // issue global loads, 16-token cover
    SBAR;
    PF(2, 2);  SBAR; ST(0, t0 + 0);
    PF(0, 3);  SBAR; ST(1, t0 + 1);
    PF(1, 4);  SBAR; ST(2, t0 + 2);
    PF(2, 5);  SBAR; ST(0, t0 + 3);
    PF(0, 6);  SBAR; ST(1, t0 + 4);
    PF(1, 7);  SBAR; ST(2, t0 + 5);
    PF(2, 8);  SBAR; ST(0, t0 + 6);
    PF(0, 9);  SBAR; ST(1, t0 + 7);
    PF(1, 10); SBAR; ST(2, t0 + 8);
    PF(2, 11); SBAR; ST(0, t0 + 9);
    PF(0, 12); SBAR; ST(1, t0 + 10);
    PF(1, 13); SBAR; ST(2, t0 + 11);
    PF(2, 14); SBAR; ST(0, t0 + 12);
    PF(0, 15); SBAR; ST(1, t0 + 13);
    ST(2, t0 + 14);
    ST(0, t0 + 15);
    __syncthreads();
    cur ^= 1;
  }
#undef PF
#undef SBAR
#undef ST
}

// ---------------- K7: GroupNorm + bonus + gate (bf16 out) -------------------
__global__ __launch_bounds__(256) void gnout_kernel(
    const float* __restrict__ y, const float* __restrict__ r,
    const float* __restrict__ kf, const float* __restrict__ v,
    const float* __restrict__ g,
    const float* __restrict__ lnw, const float* __restrict__ lnb,
    const float* __restrict__ fa, bf16* __restrict__ z) {
  int tid = threadIdx.x;
  int w = tid >> 6, lane = tid & 63;
  int gi = (blockIdx.x << 2) + w;  // (b*T+t)*H + h
  int h = gi & 15, mt = gi >> 4;
  long off = (long)mt * C_ + (h << 6) + lane;
  float yv = y[off];
  float s = yv;
  s += __shfl_xor(s, 1); s += __shfl_xor(s, 2); s += __shfl_xor(s, 4);
  s += __shfl_xor(s, 8); s += __shfl_xor(s, 16); s += __shfl_xor(s, 32);
  float mu = s * (1.0f / 64.0f);
  float d = yv - mu;
  float s2 = d * d;
  s2 += __shfl_xor(s2, 1); s2 += __shfl_xor(s2, 2); s2 += __shfl_xor(s2, 4);
  s2 += __shfl_xor(s2, 8); s2 += __shfl_xor(s2, 16); s2 += __shfl_xor(s2, 32);
  float var = s2 * (1.0f / 64.0f);
  int hc = (h << 6) + lane;
  float dot = r[off] * kf[off] * fa[hc];
  dot += __shfl_xor(dot, 1); dot += __shfl_xor(dot, 2); dot += __shfl_xor(dot, 4);
  dot += __shfl_xor(dot, 8); dot += __shfl_xor(dot, 16); dot += __shfl_xor(dot, 32);
  float yn = d * rsqrtf(var + 0.00064f) * lnw[hc] + lnb[hc];
  z[off] = f2bf((yn + dot * v[off]) * g[off]);
}

extern "C" void kernel_launch(void* const* d_in, const int* in_sizes, int n_in,
                              void* d_out, int out_size, void* d_ws, size_t ws_size,
                              hipStream_t stream) {
  const float* x = (const float*)d_in[0];
  const float* tmx = (const float*)d_in[1];
  const float* tmaa = (const float*)d_in[2];
  const float* tmw1 = (const float*)d_in[3];
  const float* tmw2 = (const float*)d_in[4];
  const float* tdec = (const float*)d_in[5];
  const float* tdw1 = (const float*)d_in[6];
  const float* tdw2 = (const float*)d_in[7];
  const float* taa5 = (const float*)d_in[8];
  const float* taw1 = (const float*)d_in[9];
  const float* taw2 = (const float*)d_in[10];
  const float* tkw1 = (const float*)d_in[11];
  const float* tkw2 = (const float*)d_in[12];
  const float* gw1 = (const float*)d_in[13];
  const float* gw2 = (const float*)d_in[14];
  const float* tmia = (const float*)d_in[15];
  const float* maw1 = (const float*)d_in[16];
  const float* maw2 = (const float*)d_in[17];
  const float* tmik = (const float*)d_in[18];
  const float* mkw1 = (const float*)d_in[19];
  const float* mkw2 = (const float*)d_in[20];
  const float* wrec = (const float*)d_in[21];
  const float* wkey = (const float*)d_in[22];
  const float* wval = (const float*)d_in[23];
  const float* wout = (const float*)d_in[24];
  const float* lnw = (const float*)d_in[25];
  const float* lnb = (const float*)d_in[26];
  const float* faaa = (const float*)d_in[27];

  const long MT = 2048, CC = 1024;
  char* base = (char*)d_ws;
  float* xx = (float*)base;    base += MT * CC * 4;   // also y
  bf16* xxxb = (bf16*)base;    base += MT * CC * 2;
  bf16* xrgb = (bf16*)base;    base += MT * CC * 2;   // ┐ kfin overlays (8MB)
  bf16* xwab = (bf16*)base;    base += MT * CC * 2;   // ┘
  bf16* xkb = (bf16*)base;     base += MT * CC * 2;   // ┐ kkn overlays (8MB)
  bf16* xvb = (bf16*)base;     base += MT * CC * 2;   // ┘
  float* rr = (float*)base;    base += MT * CC * 4;
  float* kraw = (float*)base;  base += MT * CC * 4;   // also ew
  float* vv = (float*)base;    base += MT * CC * 4;
  float* gg = (float*)base;    base += MT * CC * 4;
  float* bbo = (float*)base;   base += MT * CC * 4;
  float* mix = (float*)base;   base += MT * 128 * 4;
  bf16* g1b = (bf16*)base;     base += MT * 128 * 2;
  float* out1 = (float*)base;  base += MT * 32 * 4;   // [kk1|mk1]
  float* out2 = (float*)base;  base += MT * 96 * 4;   // [w1|a1|ma1]
  bf16* zb = (bf16*)base;      base += MT * CC * 2;
  bf16* tmw1b = (bf16*)base;   base += 128 * CC * 2;
  bf16* wrecb = (bf16*)base;   base += CC * CC * 2;
  bf16* gw1b = (bf16*)base;    base += 128 * CC * 2;
  bf16* gw2b = (bf16*)base;    base += CC * 128 * 2;
  bf16* wkeyb = (bf16*)base;   base += CC * CC * 2;
  bf16* wvalb = (bf16*)base;   base += CC * CC * 2;
  bf16* woutb = (bf16*)base;   base += CC * CC * 2;
  bf16* wskb = (bf16*)base;    base += 32 * CC * 2;
  bf16* wswab = (bf16*)base;   base += 96 * CC * 2;
  bf16* tmw2b = (bf16*)base;   base += 4 * CC * 32 * 2;
  bf16* tdw2b = (bf16*)base;   base += CC * 64 * 2;
  bf16* tkw2b = (bf16*)base;   base += CC * 16 * 2;
  bf16* taw2b = (bf16*)base;   base += CC * 16 * 2;
  bf16* maw2b = (bf16*)base;   base += CC * 16 * 2;
  bf16* mkw2b = (bf16*)base;   base += CC * 16 * 2;
  // aliases (dead-buffer reuse, verified non-overlapping in time):
  float* ew = kraw;            // fuse2 reads kraw then writes ew at same offs
  float* kfin = (float*)xrgb;  // xrg/xwa bf16 dead before fuse2
  float* kkn = (float*)xkb;    // xk/xv bf16 dead before fuse2
  float* y = xx;               // xx dead after mix4

  auto gemm_m = [&](const bf16* A, const bf16* W, float* Cf, bf16* Cb,
                    int M, int N, int K, int actN) {
    dim3 grid((N + 63) / 64, M / 64);
    gemm_mfma_kernel<<<grid, 256, 0, stream>>>(A, W, Cf, Cb, M, N, K, actN);
  };

  cvt_weights_kernel<<<4480, 256, 0, stream>>>(
      tmw1, wrec, gw1, gw2, wkey, wval, wout,
      tmw1b, wrecb, gw1b, gw2b, wkeyb, wvalb, woutb);
  cvt_small_kernel<<<128, 256, 0, stream>>>(tkw1, mkw1, tdw1, taw1, maw1,
                                            wskb, wswab);
  cvt_small2_kernel<<<256, 256, 0, stream>>>(tmw2, tdw2, tkw2, taw2, maw2, mkw2,
                                             tmw2b, tdw2b, tkw2b, taw2b,
                                             maw2b, mkw2b);
  shift_kernel<<<8192, 256, 0, stream>>>(x, tmx, xx, xxxb);
  gemm_m(xxxb, tmw1b, mix, nullptr, 2048, 128, 1024, 128);   // tanh all
  mix4_kernel<<<2048, 256, 0, stream>>>(x, xx, mix, tmaa, tmw2b,
                                        xrgb, xwab, xkb, xvb);
  gemm_m(xrgb, wrecb, rr, nullptr, 2048, 1024, 1024, 0);
  gemm_m(xrgb, gw1b, nullptr, g1b, 2048, 128, 1024, 128);    // tanh all
  gemm_m(g1b, gw2b, gg, nullptr, 2048, 1024, 128, 0);
  gemm_m(xkb, wkeyb, kraw, nullptr, 2048, 1024, 1024, 0);
  gemm_m(xkb, wskb, out1, nullptr, 2048, 32, 1024, 16);      // tanh cols<16
  gemm_m(xvb, wvalb, vv, nullptr, 2048, 1024, 1024, 0);
  gemm_m(xwab, wswab, out2, nullptr, 2048, 96, 1024, 64);    // tanh cols<64
  fuse2_kernel<<<2048, 256, 0, stream>>>(kraw, out1, out2,
                                         tdw2b, tkw2b, taw2b, maw2b, mkw2b,
                                         tdec, taa5, tmia, tmik,
                                         ew, kfin, kkn, bbo);
  scan_kernel<<<256, 128, 0, stream>>>(rr, ew, kfin, vv, kkn, bbo, y);
  gnout_kernel<<<8192, 256, 0, stream>>>(y, rr, kfin, vv, gg, lnw, lnb, faaa, zb);
  gemm_m(zb, woutb, (float*)d_out, nullptr, 2048, 1024, 1024, 0);
}

// Round 6
// 598.844 us; speedup vs baseline: 1.0917x; 1.0917x over previous
//
#include <hip/hip_runtime.h>
#include <hip/hip_bf16.h>

typedef __hip_bfloat16 bf16;

#define B_ 2
#define T_ 1024
#define C_ 1024
#define H_ 16
#define N_ 64

using short8 = __attribute__((ext_vector_type(8))) short;
using f32x4 = __attribute__((ext_vector_type(4))) float;

__device__ __forceinline__ float us2f(unsigned short u) {
  return __uint_as_float(((unsigned int)u) << 16);
}
__device__ __forceinline__ float bs2f(short s) {
  return __uint_as_float(((unsigned int)(unsigned short)s) << 16);
}
__device__ __forceinline__ bf16 f2bf(float f) { return __float2bfloat16(f); }
__device__ __forceinline__ float sigmoidf_(float x) { return 1.0f / (1.0f + expf(-x)); }
__device__ __forceinline__ float softplusf_(float x) {
  return fmaxf(x, 0.0f) + log1pf(expf(-fabsf(x)));
}
// Full 16-lane-row sum, all lanes receive the result. Pure-VALU DPP:
// quad_perm xor1, xor2 give quad sums; row_ror:4 + row_ror:8 complete it.
__device__ __forceinline__ float qsum16(float x) {
  int a = __builtin_amdgcn_update_dpp(0, __float_as_int(x), 0xB1, 0xF, 0xF, true);
  x += __int_as_float(a);                       // quad_perm [1,0,3,2] (xor 1)
  int b = __builtin_amdgcn_update_dpp(0, __float_as_int(x), 0x4E, 0xF, 0xF, true);
  x += __int_as_float(b);                       // quad_perm [2,3,0,1] (xor 2)
  int c = __builtin_amdgcn_update_dpp(0, __float_as_int(x), 0x124, 0xF, 0xF, true);
  x += __int_as_float(c);                       // row_ror:4
  int d = __builtin_amdgcn_update_dpp(0, __float_as_int(x), 0x128, 0xF, 0xF, true);
  x += __int_as_float(d);                       // row_ror:8
  return x;
}

// ---------------- K0: ALL weight fp32->bf16 conversions, one launch ---------
__global__ __launch_bounds__(256) void cvt_all_kernel(
    const float* __restrict__ s0, const float* __restrict__ s1,
    const float* __restrict__ s2, const float* __restrict__ s3,
    const float* __restrict__ s4, const float* __restrict__ s5,
    const float* __restrict__ s6,
    bf16* __restrict__ d0, bf16* __restrict__ d1, bf16* __restrict__ d2,
    bf16* __restrict__ d3, bf16* __restrict__ d4, bf16* __restrict__ d5,
    bf16* __restrict__ d6,
    const float* __restrict__ tkw1, const float* __restrict__ mkw1,
    const float* __restrict__ tdw1, const float* __restrict__ taw1,
    const float* __restrict__ maw1,
    bf16* __restrict__ wsk, bf16* __restrict__ wswa,
    const float* __restrict__ tmw2, const float* __restrict__ tdw2,
    const float* __restrict__ tkw2, const float* __restrict__ taw2,
    const float* __restrict__ maw2, const float* __restrict__ mkw2,
    bf16* __restrict__ tmw2b, bf16* __restrict__ tdw2b,
    bf16* __restrict__ tkw2b, bf16* __restrict__ taw2b,
    bf16* __restrict__ maw2b, bf16* __restrict__ mkw2b) {
  long bidx = blockIdx.x;
  const float* s; bf16* d; long off;
  if (bidx < 4480) {                      // big weights
    long i4 = bidx * 256 + threadIdx.x;
    if (i4 < 32768) { s = s0; d = d0; off = i4; }
    else if (i4 < 294912) { s = s1; d = d1; off = i4 - 32768; }
    else if (i4 < 327680) { s = s2; d = d2; off = i4 - 294912; }
    else if (i4 < 360448) { s = s3; d = d3; off = i4 - 327680; }
    else if (i4 < 622592) { s = s4; d = d4; off = i4 - 360448; }
    else if (i4 < 884736) { s = s5; d = d5; off = i4 - 622592; }
    else { s = s6; d = d6; off = i4 - 884736; }
  } else if (bidx < 4608) {               // LoRA-1 packs
    long i4 = (bidx - 4480) * 256 + threadIdx.x;  // < 32768
    long so, dof;
    if (i4 < 4096) { s = tkw1; so = i4; d = wsk; dof = i4; }
    else if (i4 < 8192) { s = mkw1; so = i4 - 4096; d = wsk; dof = i4; }
    else if (i4 < 24576) { s = tdw1; so = i4 - 8192; d = wswa; dof = i4 - 8192; }
    else if (i4 < 28672) { s = taw1; so = i4 - 24576; d = wswa; dof = i4 - 8192; }
    else { s = maw1; so = i4 - 28672; d = wswa; dof = i4 - 8192; }
    float4 v = *(const float4*)(s + so * 4);
    d[dof * 4 + 0] = f2bf(v.x); d[dof * 4 + 1] = f2bf(v.y);
    d[dof * 4 + 2] = f2bf(v.z); d[dof * 4 + 3] = f2bf(v.w);
    return;
  } else {                                // LoRA-2 packs
    long i4 = (bidx - 4608) * 256 + threadIdx.x;  // < 65536
    if (i4 < 32768) { s = tmw2; d = tmw2b; off = i4; }
    else if (i4 < 49152) { s = tdw2; d = tdw2b; off = i4 - 32768; }
    else if (i4 < 53248) { s = tkw2; d = tkw2b; off = i4 - 49152; }
    else if (i4 < 57344) { s = taw2; d = taw2b; off = i4 - 53248; }
    else if (i4 < 61440) { s = maw2; d = maw2b; off = i4 - 57344; }
    else { s = mkw2; d = mkw2b; off = i4 - 61440; }
  }
  float4 v = *(const float4*)(s + off * 4);
  d[off * 4 + 0] = f2bf(v.x);
  d[off * 4 + 1] = f2bf(v.y);
  d[off * 4 + 2] = f2bf(v.z);
  d[off * 4 + 3] = f2bf(v.w);
}

// ---------------- K1: token shift (writes xx f32, xxx bf16) -----------------
__global__ __launch_bounds__(256) void shift_kernel(
    const float* __restrict__ x, const float* __restrict__ tmx,
    float* __restrict__ xx, bf16* __restrict__ xxxb) {
  long idx = (long)blockIdx.x * 256 + threadIdx.x;  // < B*T*C
  int c = (int)(idx & (C_ - 1));
  int t = (int)((idx >> 10) & (T_ - 1));
  float xv = x[idx];
  float xp = (t > 0) ? x[idx - C_] : 0.0f;
  float d = xp - xv;
  xx[idx] = d;
  xxxb[idx] = f2bf(xv + d * tmx[c]);
}

// ---------------- Batched MFMA GEMM: C[z] = A[z] * W[z]^T -------------------
// 128x64 tile, 4 waves each owning 32 rows (2 M-frags x 4 N-frags = 8 accs,
// 16 MFMA per 64-K step/wave). Up to 6 GEMMs batched by blockIdx.z.
// R5 bug fixed here: staging must fill the FULL tile each K-step --
// A: 128x64 bf16 = 32/thread (4 consecutive short8 per thread),
// W: 64x64 bf16 = 16/thread (2 consecutive short8 per thread, the verified
// 64x64-kernel pattern). R5 wrote only half of As/Ws -> MFMA read garbage.
struct GemmBatch {
  const bf16* A[6]; const bf16* W[6];
  float* Cf[6]; bf16* Cb[6];
  int N[6]; int actN[6];
};

__global__ __launch_bounds__(256) void gemm_batch_kernel(GemmBatch gb, int K) {
  __shared__ __align__(16) bf16 As[128][72];  // padded rows: conflict-free reads
  __shared__ __align__(16) bf16 Ws[64][72];
  int z = blockIdx.z;
  int Nz = gb.N[z];
  int n0 = blockIdx.x << 6;
  if (n0 >= Nz) return;
  int m0 = blockIdx.y << 7;
  int actN = gb.actN[z];
  const bf16* A = gb.A[z];
  const bf16* W = gb.W[z];
  float* Cf = gb.Cf[z];
  bf16* Cb = gb.Cb[z];
  int tid = threadIdx.x;
  int arow = tid >> 1, acol = (tid & 1) << 5;   // A: 2 threads/row, 32 cols each
  int wrow = tid >> 2, wcol = (tid & 3) << 4;   // W: 4 threads/row, 16 cols each
  int wv = tid >> 6, lane = tid & 63;
  int fr = lane & 15, fq = lane >> 4;
  bool wok = (n0 + wrow) < Nz;
  const bf16* Ap = A + (long)(m0 + arow) * K + acol;
  const bf16* Wp = W + (long)(n0 + wrow) * K + wcol;
  short8 zz = {0, 0, 0, 0, 0, 0, 0, 0};
  f32x4 a00 = {0.f, 0.f, 0.f, 0.f};
  f32x4 a01 = a00, a02 = a00, a03 = a00, a10 = a00, a11 = a00, a12 = a00, a13 = a00;
  for (int k0 = 0; k0 < K; k0 += 64) {
    *(short8*)&As[arow][acol] = *(const short8*)(Ap + k0);
    *(short8*)&As[arow][acol + 8] = *(const short8*)(Ap + k0 + 8);
    *(short8*)&As[arow][acol + 16] = *(const short8*)(Ap + k0 + 16);
    *(short8*)&As[arow][acol + 24] = *(const short8*)(Ap + k0 + 24);
    *(short8*)&Ws[wrow][wcol] = wok ? *(const short8*)(Wp + k0) : zz;
    *(short8*)&Ws[wrow][wcol + 8] = wok ? *(const short8*)(Wp + k0 + 8) : zz;
    __syncthreads();
#pragma unroll
    for (int kk = 0; kk < 2; kk++) {
      int ko = (fq << 3) + (kk << 5);
      short8 af0 = *(const short8*)&As[(wv << 5) + fr][ko];
      short8 af1 = *(const short8*)&As[(wv << 5) + 16 + fr][ko];
      short8 b0 = *(const short8*)&Ws[fr][ko];
      short8 b1 = *(const short8*)&Ws[16 + fr][ko];
      short8 b2 = *(const short8*)&Ws[32 + fr][ko];
      short8 b3 = *(const short8*)&Ws[48 + fr][ko];
      a00 = __builtin_amdgcn_mfma_f32_16x16x32_bf16(af0, b0, a00, 0, 0, 0);
      a01 = __builtin_amdgcn_mfma_f32_16x16x32_bf16(af0, b1, a01, 0, 0, 0);
      a02 = __builtin_amdgcn_mfma_f32_16x16x32_bf16(af0, b2, a02, 0, 0, 0);
      a03 = __builtin_amdgcn_mfma_f32_16x16x32_bf16(af0, b3, a03, 0, 0, 0);
      a10 = __builtin_amdgcn_mfma_f32_16x16x32_bf16(af1, b0, a10, 0, 0, 0);
      a11 = __builtin_amdgcn_mfma_f32_16x16x32_bf16(af1, b1, a11, 0, 0, 0);
      a12 = __builtin_amdgcn_mfma_f32_16x16x32_bf16(af1, b2, a12, 0, 0, 0);
      a13 = __builtin_amdgcn_mfma_f32_16x16x32_bf16(af1, b3, a13, 0, 0, 0);
    }
    __syncthreads();
  }
  int ocol = n0 + fr;
  int orow0 = m0 + (wv << 5) + (fq << 2);
#define WRB(accv, mf, nt) { int col = ocol + ((nt) << 4); if (col < Nz) { \
    _Pragma("unroll") for (int r = 0; r < 4; r++) { \
      float vvv = accv[r]; if (col < actN) vvv = tanhf(vvv); \
      long oi = (long)(orow0 + ((mf) << 4) + r) * Nz + col; \
      if (Cb) Cb[oi] = f2bf(vvv); else Cf[oi] = vvv; } } }
  WRB(a00, 0, 0) WRB(a01, 0, 1) WRB(a02, 0, 2) WRB(a03, 0, 3)
  WRB(a10, 1, 0) WRB(a11, 1, 1) WRB(a12, 1, 2) WRB(a13, 1, 3)
#undef WRB
}

// ---------------- K3: deltas + build xrg/xwa/xk/xv (bf16 out) ---------------
__global__ __launch_bounds__(256) void mix4_kernel(
    const float* __restrict__ x, const float* __restrict__ xx,
    const float* __restrict__ mix, const float* __restrict__ tmaa,
    const bf16* __restrict__ w2b,
    bf16* __restrict__ xrg, bf16* __restrict__ xwa,
    bf16* __restrict__ xk, bf16* __restrict__ xv) {
  int m = blockIdx.x;
  int tid = threadIdx.x;
  __shared__ float mrow[128];
  if (tid < 128) mrow[tid] = mix[(long)m * 128 + tid];
  __syncthreads();
#pragma unroll
  for (int cc = 0; cc < 4; cc++) {
    int c = tid + (cc << 8);
    long off = (long)m * C_ + c;
    float xb = x[off];
    float xxv = xx[off];
    float res[4];
#pragma unroll
    for (int f = 0; f < 4; f++) {
      const short8* wp = (const short8*)(w2b + (((long)f * C_ + c) << 5));
      float dl = 0.f;
#pragma unroll
      for (int d8 = 0; d8 < 4; d8++) {
        short8 u = wp[d8];
        int db = (f << 5) + (d8 << 3);
#pragma unroll
        for (int e = 0; e < 8; e++) dl += mrow[db + e] * bs2f(u[e]);
      }
      res[f] = xb + xxv * (tmaa[f * C_ + c] + dl);
    }
    xrg[off] = f2bf(res[0]); xwa[off] = f2bf(res[1]);
    xk[off] = f2bf(res[2]); xv[off] = f2bf(res[3]);
  }
}

// ---------------- K5: stage-2 small GEMMs + gates + per-head kk norm --------
__global__ __launch_bounds__(256) void fuse2_kernel(
    const float* __restrict__ kraw, const float* __restrict__ out1,
    const float* __restrict__ out2,
    const bf16* __restrict__ dw2, const bf16* __restrict__ kkw2,
    const bf16* __restrict__ aw2, const bf16* __restrict__ maw2,
    const bf16* __restrict__ mkw2,
    const float* __restrict__ tdec, const float* __restrict__ taa,
    const float* __restrict__ tma, const float* __restrict__ tmk,
    float* __restrict__ ew, float* __restrict__ kfin,
    float* __restrict__ kkn, float* __restrict__ bbo) {
  int m = blockIdx.x, tid = threadIdx.x;
  __shared__ float w1r[64], kk1r[16], a1r[16], ma1r[16], mk1r[16];
  if (tid < 64) w1r[tid] = out2[(long)m * 96 + tid];
  else if (tid < 80) kk1r[tid - 64] = out1[(long)m * 32 + (tid - 64)];
  else if (tid < 96) a1r[tid - 80] = out2[(long)m * 96 + 64 + (tid - 80)];
  else if (tid < 112) ma1r[tid - 96] = out2[(long)m * 96 + 80 + (tid - 96)];
  else if (tid < 128) mk1r[tid - 112] = out1[(long)m * 32 + 16 + (tid - 112)];
  __syncthreads();
  float kkp[4], av[4], wv[4], kr[4], mkv[4];
  float sumsq = 0.f;
#pragma unroll
  for (int j = 0; j < 4; j++) {
    int c = (tid << 2) + j;
    long off = (long)m * C_ + c;
    float wd = 0.f;
    const short8* dp = (const short8*)(dw2 + ((long)c << 6));
#pragma unroll
    for (int d8 = 0; d8 < 8; d8++) {
      short8 u = dp[d8];
      int db = d8 << 3;
#pragma unroll
      for (int e = 0; e < 8; e++) wd += w1r[db + e] * bs2f(u[e]);
    }
    float w = -softplusf_(-(tdec[c] + wd)) - 0.5f;
    wv[j] = w;
    float kd = 0.f, ad = 0.f, mad = 0.f, mkd = 0.f;
    const short8* kp = (const short8*)(kkw2 + ((long)c << 4));
    const short8* ap = (const short8*)(aw2 + ((long)c << 4));
    const short8* mp = (const short8*)(maw2 + ((long)c << 4));
    const short8* qp = (const short8*)(mkw2 + ((long)c << 4));
#pragma unroll
    for (int d8 = 0; d8 < 2; d8++) {
      short8 u1 = kp[d8], u2 = ap[d8], u3 = mp[d8], u4 = qp[d8];
      int db = d8 << 3;
#pragma unroll
      for (int e = 0; e < 8; e++) {
        kd += kk1r[db + e] * bs2f(u1[e]);
        ad += a1r[db + e] * bs2f(u2[e]);
        mad += ma1r[db + e] * bs2f(u3[e]);
        mkd += mk1r[db + e] * bs2f(u4[e]);
      }
    }
    float krw = kraw[off];
    float kkpre = krw + kd;
    kkp[j] = kkpre;
    sumsq += kkpre * kkpre;
    float a = sigmoidf_(taa[c] + ad);
    av[j] = a;
    float ma = sigmoidf_(tma[c] + mad);
    float mk = sigmoidf_(tmk[c] + mkd);
    mkv[j] = mk;
    kr[j] = krw * (ma + a * (1.f - ma));
  }
  sumsq += __shfl_xor(sumsq, 1);
  sumsq += __shfl_xor(sumsq, 2);
  sumsq += __shfl_xor(sumsq, 4);
  sumsq += __shfl_xor(sumsq, 8);
  float rn = 1.0f / fmaxf(sqrtf(sumsq), 1e-12f);
#pragma unroll
  for (int j = 0; j < 4; j++) {
    int c = (tid << 2) + j;
    long off = (long)m * C_ + c;
    float kknv = kkp[j] * rn;
    kkn[off] = kknv;
    bbo[off] = -kknv * av[j];
    ew[off] = expf(wv[j]);
    kfin[off] = kr[j] * expf(wv[j] * mkv[j]);
  }
}

// ---------------- K6: RWKV-7 scan, 128 blocks x 256 threads -----------------
// Verified-best config (R3, 134 us). block = (b,h,rowgroup of 16 rows); lane
// = g*16+q: row = rg*16 + wave*4 + g, keys 4q..4q+3 -> S[4]/lane; qsum16 DPP
// reductions. Double-buffered LDS (barrier per 16-token chunk), 3-set rotating
// register pipeline 2 tokens ahead, sched_barrier(0x7) pins DS order. R4's
// repacking test (2 waves/CU) proved the scan is NOT LDS-pipe-bound; ~310
// cyc/token is the exposed-latency+dep-chain floor of this structure.
#define SCHUNK 16
#define NCHUNK (T_ / SCHUNK)
__global__ __launch_bounds__(256, 1) void scan_kernel(
    const float* __restrict__ rB, const float* __restrict__ ewB,
    const float* __restrict__ kB, const float* __restrict__ vB,
    const float* __restrict__ kkB, const float* __restrict__ bbB,
    float* __restrict__ yB) {
  __shared__ __align__(16) float lds[2][6][SCHUNK * 64];
  int bid = blockIdx.x;          // 0..127
  int bh = bid >> 2, rg = bid & 3;
  int b = bh >> 4, h = bh & 15;
  int tid = threadIdx.x;
  int wave = tid >> 6, lane = tid & 63;
  int g = lane >> 4, q = lane & 15;
  int row = (rg << 4) + (wave << 2) + g;   // this lane's single row
  int kq = q << 2;                         // 4 keys: kq..kq+3
  const long base = ((long)b * T_) * C_ + (h << 6);
  const float* s0 = kkB + base;
  const float* s1 = ewB + base;
  const float* s2 = kB + base;
  const float* s3 = bbB + base;
  const float* s4 = rB + base;
  const float* s5 = vB + base;
  int stok = tid >> 4;           // staging token within chunk (0..15)
  int spc = (tid & 15) << 2;     // float offset within token row
  int lo = (stok << 6) + spc;    // LDS float offset
  float4 rb0, rb1, rb2, rb3, rb4, rb5;
  auto loadc = [&](int c) {
    long go = (long)((c << 4) + stok) * C_ + spc;
    rb0 = *(const float4*)(s0 + go);
    rb1 = *(const float4*)(s1 + go);
    rb2 = *(const float4*)(s2 + go);
    rb3 = *(const float4*)(s3 + go);
    rb4 = *(const float4*)(s4 + go);
    rb5 = *(const float4*)(s5 + go);
  };
  auto stage = [&](int buf) {
    *(float4*)&lds[buf][0][lo] = rb0;
    *(float4*)&lds[buf][1][lo] = rb1;
    *(float4*)&lds[buf][2][lo] = rb2;
    *(float4*)&lds[buf][3][lo] = rb3;
    *(float4*)&lds[buf][4][lo] = rb4;
    *(float4*)&lds[buf][5][lo] = rb5;
  };
  float S0 = 0.f, S1 = 0.f, S2 = 0.f, S3 = 0.f;
  // 3 rotating prefetch sets (static names; token tt uses set tt%3)
  float4 Q0kk, Q0ew, Q0k, Q0bb, Q0r; float Q0v;
  float4 Q1kk, Q1ew, Q1k, Q1bb, Q1r; float Q1v;
  float4 Q2kk, Q2ew, Q2k, Q2bb, Q2r; float Q2v;

#define PF(i, tt) { int tb_ = ((tt) << 6); \
    Q##i##kk = *(const float4*)&lds[cur][0][tb_ + kq]; \
    Q##i##ew = *(const float4*)&lds[cur][1][tb_ + kq]; \
    Q##i##k  = *(const float4*)&lds[cur][2][tb_ + kq]; \
    Q##i##bb = *(const float4*)&lds[cur][3][tb_ + kq]; \
    Q##i##r  = *(const float4*)&lds[cur][4][tb_ + kq]; \
    Q##i##v  = lds[cur][5][tb_ + row]; }
#define SBAR __builtin_amdgcn_sched_barrier(0x7)
#define ST(i, gtok) { \
    float p_ = fmaf(S1, Q##i##kk.y, S0 * Q##i##kk.x) + \
               fmaf(S3, Q##i##kk.w, S2 * Q##i##kk.z); \
    float sab = qsum16(p_); \
    float n0 = fmaf(S0, Q##i##ew.x, Q##i##v * Q##i##k.x); \
    float n1 = fmaf(S1, Q##i##ew.y, Q##i##v * Q##i##k.y); \
    float n2 = fmaf(S2, Q##i##ew.z, Q##i##v * Q##i##k.z); \
    float n3 = fmaf(S3, Q##i##ew.w, Q##i##v * Q##i##k.w); \
    S0 = fmaf(sab, Q##i##bb.x, n0); \
    S1 = fmaf(sab, Q##i##bb.y, n1); \
    S2 = fmaf(sab, Q##i##bb.z, n2); \
    S3 = fmaf(sab, Q##i##bb.w, n3); \
    float yp_ = fmaf(S1, Q##i##r.y, S0 * Q##i##r.x) + \
                fmaf(S3, Q##i##r.w, S2 * Q##i##r.z); \
    float yv_ = qsum16(yp_); \
    if (q == 0) yB[base + (long)(gtok) * C_ + row] = yv_; }

  // prologue: chunk 0 -> buf0; chunk 1 loaded into regs
  loadc(0);
  stage(0);
  loadc(1);
  __syncthreads();
  int cur = 0;
  for (int c = 0; c < NCHUNK; c++) {
    int t0 = c << 4;
    // prefetch tokens 0,1 of this chunk (reads queue before the stage writes)
    PF(0, 0); PF(1, 1);
    if (c + 1 < NCHUNK) stage(cur ^ 1);   // regs hold chunk c+1
    if (c + 2 < NCHUNK) loadc(c + 2);     // issue global loads, 16-token cover
    SBAR;
    PF(2, 2);  SBAR; ST(0, t0 + 0);
    PF(0, 3);  SBAR; ST(1, t0 + 1);
    PF(1, 4);  SBAR; ST(2, t0 + 2);
    PF(2, 5);  SBAR; ST(0, t0 + 3);
    PF(0, 6);  SBAR; ST(1, t0 + 4);
    PF(1, 7);  SBAR; ST(2, t0 + 5);
    PF(2, 8);  SBAR; ST(0, t0 + 6);
    PF(0, 9);  SBAR; ST(1, t0 + 7);
    PF(1, 10); SBAR; ST(2, t0 + 8);
    PF(2, 11); SBAR; ST(0, t0 + 9);
    PF(0, 12); SBAR; ST(1, t0 + 10);
    PF(1, 13); SBAR; ST(2, t0 + 11);
    PF(2, 14); SBAR; ST(0, t0 + 12);
    PF(0, 15); SBAR; ST(1, t0 + 13);
    ST(2, t0 + 14);
    ST(0, t0 + 15);
    __syncthreads();
    cur ^= 1;
  }
#undef PF
#undef SBAR
#undef ST
}

// ---------------- K7: GroupNorm + bonus + gate (bf16 out) -------------------
__global__ __launch_bounds__(256) void gnout_kernel(
    const float* __restrict__ y, const float* __restrict__ r,
    const float* __restrict__ kf, const float* __restrict__ v,
    const float* __restrict__ g,
    const float* __restrict__ lnw, const float* __restrict__ lnb,
    const float* __restrict__ fa, bf16* __restrict__ z) {
  int tid = threadIdx.x;
  int w = tid >> 6, lane = tid & 63;
  int gi = (blockIdx.x << 2) + w;  // (b*T+t)*H + h
  int h = gi & 15, mt = gi >> 4;
  long off = (long)mt * C_ + (h << 6) + lane;
  float yv = y[off];
  float s = yv;
  s += __shfl_xor(s, 1); s += __shfl_xor(s, 2); s += __shfl_xor(s, 4);
  s += __shfl_xor(s, 8); s += __shfl_xor(s, 16); s += __shfl_xor(s, 32);
  float mu = s * (1.0f / 64.0f);
  float d = yv - mu;
  float s2 = d * d;
  s2 += __shfl_xor(s2, 1); s2 += __shfl_xor(s2, 2); s2 += __shfl_xor(s2, 4);
  s2 += __shfl_xor(s2, 8); s2 += __shfl_xor(s2, 16); s2 += __shfl_xor(s2, 32);
  float var = s2 * (1.0f / 64.0f);
  int hc = (h << 6) + lane;
  float dot = r[off] * kf[off] * fa[hc];
  dot += __shfl_xor(dot, 1); dot += __shfl_xor(dot, 2); dot += __shfl_xor(dot, 4);
  dot += __shfl_xor(dot, 8); dot += __shfl_xor(dot, 16); dot += __shfl_xor(dot, 32);
  float yn = d * rsqrtf(var + 0.00064f) * lnw[hc] + lnb[hc];
  z[off] = f2bf((yn + dot * v[off]) * g[off]);
}

extern "C" void kernel_launch(void* const* d_in, const int* in_sizes, int n_in,
                              void* d_out, int out_size, void* d_ws, size_t ws_size,
                              hipStream_t stream) {
  const float* x = (const float*)d_in[0];
  const float* tmx = (const float*)d_in[1];
  const float* tmaa = (const float*)d_in[2];
  const float* tmw1 = (const float*)d_in[3];
  const float* tmw2 = (const float*)d_in[4];
  const float* tdec = (const float*)d_in[5];
  const float* tdw1 = (const float*)d_in[6];
  const float* tdw2 = (const float*)d_in[7];
  const float* taa5 = (const float*)d_in[8];
  const float* taw1 = (const float*)d_in[9];
  const float* taw2 = (const float*)d_in[10];
  const float* tkw1 = (const float*)d_in[11];
  const float* tkw2 = (const float*)d_in[12];
  const float* gw1 = (const float*)d_in[13];
  const float* gw2 = (const float*)d_in[14];
  const float* tmia = (const float*)d_in[15];
  const float* maw1 = (const float*)d_in[16];
  const float* maw2 = (const float*)d_in[17];
  const float* tmik = (const float*)d_in[18];
  const float* mkw1 = (const float*)d_in[19];
  const float* mkw2 = (const float*)d_in[20];
  const float* wrec = (const float*)d_in[21];
  const float* wkey = (const float*)d_in[22];
  const float* wval = (const float*)d_in[23];
  const float* wout = (const float*)d_in[24];
  const float* lnw = (const float*)d_in[25];
  const float* lnb = (const float*)d_in[26];
  const float* faaa = (const float*)d_in[27];

  const long MT = 2048, CC = 1024;
  char* base = (char*)d_ws;
  float* xx = (float*)base;    base += MT * CC * 4;   // also y
  bf16* xxxb = (bf16*)base;    base += MT * CC * 2;
  bf16* xrgb = (bf16*)base;    base += MT * CC * 2;   // ┐ kfin overlays (8MB)
  bf16* xwab = (bf16*)base;    base += MT * CC * 2;   // ┘
  bf16* xkb = (bf16*)base;     base += MT * CC * 2;   // ┐ kkn overlays (8MB)
  bf16* xvb = (bf16*)base;     base += MT * CC * 2;   // ┘
  float* rr = (float*)base;    base += MT * CC * 4;
  float* kraw = (float*)base;  base += MT * CC * 4;   // also ew
  float* vv = (float*)base;    base += MT * CC * 4;
  float* gg = (float*)base;    base += MT * CC * 4;
  float* bbo = (float*)base;   base += MT * CC * 4;
  float* mix = (float*)base;   base += MT * 128 * 4;
  bf16* g1b = (bf16*)base;     base += MT * 128 * 2;
  float* out1 = (float*)base;  base += MT * 32 * 4;   // [kk1|mk1]
  float* out2 = (float*)base;  base += MT * 96 * 4;   // [w1|a1|ma1]
  bf16* zb = (bf16*)base;      base += MT * CC * 2;
  bf16* tmw1b = (bf16*)base;   base += 128 * CC * 2;
  bf16* wrecb = (bf16*)base;   base += CC * CC * 2;
  bf16* gw1b = (bf16*)base;    base += 128 * CC * 2;
  bf16* gw2b = (bf16*)base;    base += CC * 128 * 2;
  bf16* wkeyb = (bf16*)base;   base += CC * CC * 2;
  bf16* wvalb = (bf16*)base;   base += CC * CC * 2;
  bf16* woutb = (bf16*)base;   base += CC * CC * 2;
  bf16* wskb = (bf16*)base;    base += 32 * CC * 2;
  bf16* wswab = (bf16*)base;   base += 96 * CC * 2;
  bf16* tmw2b = (bf16*)base;   base += 4 * CC * 32 * 2;
  bf16* tdw2b = (bf16*)base;   base += CC * 64 * 2;
  bf16* tkw2b = (bf16*)base;   base += CC * 16 * 2;
  bf16* taw2b = (bf16*)base;   base += CC * 16 * 2;
  bf16* maw2b = (bf16*)base;   base += CC * 16 * 2;
  bf16* mkw2b = (bf16*)base;   base += CC * 16 * 2;
  // aliases (dead-buffer reuse, verified non-overlapping in time):
  float* ew = kraw;            // fuse2 reads kraw then writes ew at same offs
  float* kfin = (float*)xrgb;  // xrg/xwa bf16 dead before fuse2
  float* kkn = (float*)xkb;    // xk/xv bf16 dead before fuse2
  float* y = xx;               // xx dead after mix4

  cvt_all_kernel<<<4864, 256, 0, stream>>>(
      tmw1, wrec, gw1, gw2, wkey, wval, wout,
      tmw1b, wrecb, gw1b, gw2b, wkeyb, wvalb, woutb,
      tkw1, mkw1, tdw1, taw1, maw1, wskb, wswab,
      tmw2, tdw2, tkw2, taw2, maw2, mkw2,
      tmw2b, tdw2b, tkw2b, taw2b, maw2b, mkw2b);
  shift_kernel<<<8192, 256, 0, stream>>>(x, tmx, xx, xxxb);

  // mix GEMM: (2048x1024)x(128x1024)^T, tanh all
  {
    GemmBatch gb = {};
    gb.A[0] = xxxb; gb.W[0] = tmw1b; gb.Cf[0] = mix; gb.Cb[0] = nullptr;
    gb.N[0] = 128; gb.actN[0] = 128;
    gemm_batch_kernel<<<dim3(2, 16, 1), 256, 0, stream>>>(gb, 1024);
  }
  mix4_kernel<<<2048, 256, 0, stream>>>(x, xx, mix, tmaa, tmw2b,
                                        xrgb, xwab, xkb, xvb);
  // 6 independent K=1024 GEMMs, one launch
  {
    GemmBatch gb = {};
    gb.A[0] = xrgb; gb.W[0] = wrecb; gb.Cf[0] = rr;   gb.Cb[0] = nullptr; gb.N[0] = 1024; gb.actN[0] = 0;
    gb.A[1] = xrgb; gb.W[1] = gw1b;  gb.Cf[1] = nullptr; gb.Cb[1] = g1b;  gb.N[1] = 128;  gb.actN[1] = 128;
    gb.A[2] = xkb;  gb.W[2] = wkeyb; gb.Cf[2] = kraw; gb.Cb[2] = nullptr; gb.N[2] = 1024; gb.actN[2] = 0;
    gb.A[3] = xkb;  gb.W[3] = wskb;  gb.Cf[3] = out1; gb.Cb[3] = nullptr; gb.N[3] = 32;   gb.actN[3] = 16;
    gb.A[4] = xvb;  gb.W[4] = wvalb; gb.Cf[4] = vv;   gb.Cb[4] = nullptr; gb.N[4] = 1024; gb.actN[4] = 0;
    gb.A[5] = xwab; gb.W[5] = wswab; gb.Cf[5] = out2; gb.Cb[5] = nullptr; gb.N[5] = 96;   gb.actN[5] = 64;
    gemm_batch_kernel<<<dim3(16, 16, 6), 256, 0, stream>>>(gb, 1024);
  }
  // gg GEMM: (2048x128)x(1024x128)^T
  {
    GemmBatch gb = {};
    gb.A[0] = g1b; gb.W[0] = gw2b; gb.Cf[0] = gg; gb.Cb[0] = nullptr;
    gb.N[0] = 1024; gb.actN[0] = 0;
    gemm_batch_kernel<<<dim3(16, 16, 1), 256, 0, stream>>>(gb, 128);
  }
  fuse2_kernel<<<2048, 256, 0, stream>>>(kraw, out1, out2,
                                         tdw2b, tkw2b, taw2b, maw2b, mkw2b,
                                         tdec, taa5, tmia, tmik,
                                         ew, kfin, kkn, bbo);
  scan_kernel<<<128, 256, 0, stream>>>(rr, ew, kfin, vv, kkn, bbo, y);
  gnout_kernel<<<8192, 256, 0, stream>>>(y, rr, kfin, vv, gg, lnw, lnb, faaa, zb);
  // output GEMM: (2048x1024)x(1024x1024)^T
  {
    GemmBatch gb = {};
    gb.A[0] = zb; gb.W[0] = woutb; gb.Cf[0] = (float*)d_out; gb.Cb[0] = nullptr;
    gb.N[0] = 1024; gb.actN[0] = 0;
    gemm_batch_kernel<<<dim3(16, 16, 1), 256, 0, stream>>>(gb, 1024);
  }
}

// Round 7
// 545.129 us; speedup vs baseline: 1.1993x; 1.0985x over previous
//
#include <hip/hip_runtime.h>
#include <hip/hip_bf16.h>

typedef __hip_bfloat16 bf16;

#define B_ 2
#define T_ 1024
#define C_ 1024
#define H_ 16
#define N_ 64

using short8 = __attribute__((ext_vector_type(8))) short;
using f32x4 = __attribute__((ext_vector_type(4))) float;

__device__ __forceinline__ float us2f(unsigned short u) {
  return __uint_as_float(((unsigned int)u) << 16);
}
__device__ __forceinline__ float bs2f(short s) {
  return __uint_as_float(((unsigned int)(unsigned short)s) << 16);
}
__device__ __forceinline__ bf16 f2bf(float f) { return __float2bfloat16(f); }
__device__ __forceinline__ short bfbits(float f) {
  bf16 h = __float2bfloat16(f);
  return *reinterpret_cast<short*>(&h);
}
__device__ __forceinline__ float sigmoidf_(float x) { return 1.0f / (1.0f + expf(-x)); }
__device__ __forceinline__ float softplusf_(float x) {
  return fmaxf(x, 0.0f) + log1pf(expf(-fabsf(x)));
}
// Full 16-lane-row sum, all lanes receive the result. Pure-VALU DPP:
// quad_perm xor1, xor2 give quad sums; row_ror:4 + row_ror:8 complete it.
__device__ __forceinline__ float qsum16(float x) {
  int a = __builtin_amdgcn_update_dpp(0, __float_as_int(x), 0xB1, 0xF, 0xF, true);
  x += __int_as_float(a);                       // quad_perm [1,0,3,2] (xor 1)
  int b = __builtin_amdgcn_update_dpp(0, __float_as_int(x), 0x4E, 0xF, 0xF, true);
  x += __int_as_float(b);                       // quad_perm [2,3,0,1] (xor 2)
  int c = __builtin_amdgcn_update_dpp(0, __float_as_int(x), 0x124, 0xF, 0xF, true);
  x += __int_as_float(c);                       // row_ror:4
  int d = __builtin_amdgcn_update_dpp(0, __float_as_int(x), 0x128, 0xF, 0xF, true);
  x += __int_as_float(d);                       // row_ror:8
  return x;
}
// Two interleaved 16-lane-row sums. The two dependent DPP chains alternate in
// program order, so with in-order issue each chain's latency hides under the
// other's. Used by the scan to overlap token t's sab-reduction with token
// t-1's y-reduction (R7: in-order execution made the y chain serialize in
// front of the next token even though it's off the recurrence path).
__device__ __forceinline__ void qsum16x2(float& x, float& y) {
  int a0 = __builtin_amdgcn_update_dpp(0, __float_as_int(x), 0xB1, 0xF, 0xF, true);
  int b0 = __builtin_amdgcn_update_dpp(0, __float_as_int(y), 0xB1, 0xF, 0xF, true);
  x += __int_as_float(a0); y += __int_as_float(b0);
  int a1 = __builtin_amdgcn_update_dpp(0, __float_as_int(x), 0x4E, 0xF, 0xF, true);
  int b1 = __builtin_amdgcn_update_dpp(0, __float_as_int(y), 0x4E, 0xF, 0xF, true);
  x += __int_as_float(a1); y += __int_as_float(b1);
  int a2 = __builtin_amdgcn_update_dpp(0, __float_as_int(x), 0x124, 0xF, 0xF, true);
  int b2 = __builtin_amdgcn_update_dpp(0, __float_as_int(y), 0x124, 0xF, 0xF, true);
  x += __int_as_float(a2); y += __int_as_float(b2);
  int a3 = __builtin_amdgcn_update_dpp(0, __float_as_int(x), 0x128, 0xF, 0xF, true);
  int b3 = __builtin_amdgcn_update_dpp(0, __float_as_int(y), 0x128, 0xF, 0xF, true);
  x += __int_as_float(a3); y += __int_as_float(b3);
}

// ---------------- K0: ALL weight fp32->bf16 conversions, one launch ---------
__global__ __launch_bounds__(256) void cvt_all_kernel(
    const float* __restrict__ s0, const float* __restrict__ s1,
    const float* __restrict__ s2, const float* __restrict__ s3,
    const float* __restrict__ s4, const float* __restrict__ s5,
    const float* __restrict__ s6,
    bf16* __restrict__ d0, bf16* __restrict__ d1, bf16* __restrict__ d2,
    bf16* __restrict__ d3, bf16* __restrict__ d4, bf16* __restrict__ d5,
    bf16* __restrict__ d6,
    const float* __restrict__ tkw1, const float* __restrict__ mkw1,
    const float* __restrict__ tdw1, const float* __restrict__ taw1,
    const float* __restrict__ maw1,
    bf16* __restrict__ wsk, bf16* __restrict__ wswa,
    const float* __restrict__ tmw2, const float* __restrict__ tdw2,
    const float* __restrict__ tkw2, const float* __restrict__ taw2,
    const float* __restrict__ maw2, const float* __restrict__ mkw2,
    bf16* __restrict__ tmw2b, bf16* __restrict__ tdw2b,
    bf16* __restrict__ tkw2b, bf16* __restrict__ taw2b,
    bf16* __restrict__ maw2b, bf16* __restrict__ mkw2b) {
  long bidx = blockIdx.x;
  const float* s; bf16* d; long off;
  if (bidx < 4480) {                      // big weights
    long i4 = bidx * 256 + threadIdx.x;
    if (i4 < 32768) { s = s0; d = d0; off = i4; }
    else if (i4 < 294912) { s = s1; d = d1; off = i4 - 32768; }
    else if (i4 < 327680) { s = s2; d = d2; off = i4 - 294912; }
    else if (i4 < 360448) { s = s3; d = d3; off = i4 - 327680; }
    else if (i4 < 622592) { s = s4; d = d4; off = i4 - 360448; }
    else if (i4 < 884736) { s = s5; d = d5; off = i4 - 622592; }
    else { s = s6; d = d6; off = i4 - 884736; }
  } else if (bidx < 4608) {               // LoRA-1 packs
    long i4 = (bidx - 4480) * 256 + threadIdx.x;  // < 32768
    long so, dof;
    if (i4 < 4096) { s = tkw1; so = i4; d = wsk; dof = i4; }
    else if (i4 < 8192) { s = mkw1; so = i4 - 4096; d = wsk; dof = i4; }
    else if (i4 < 24576) { s = tdw1; so = i4 - 8192; d = wswa; dof = i4 - 8192; }
    else if (i4 < 28672) { s = taw1; so = i4 - 24576; d = wswa; dof = i4 - 8192; }
    else { s = maw1; so = i4 - 28672; d = wswa; dof = i4 - 8192; }
    float4 v = *(const float4*)(s + so * 4);
    d[dof * 4 + 0] = f2bf(v.x); d[dof * 4 + 1] = f2bf(v.y);
    d[dof * 4 + 2] = f2bf(v.z); d[dof * 4 + 3] = f2bf(v.w);
    return;
  } else {                                // LoRA-2 packs
    long i4 = (bidx - 4608) * 256 + threadIdx.x;  // < 65536
    if (i4 < 32768) { s = tmw2; d = tmw2b; off = i4; }
    else if (i4 < 49152) { s = tdw2; d = tdw2b; off = i4 - 32768; }
    else if (i4 < 53248) { s = tkw2; d = tkw2b; off = i4 - 49152; }
    else if (i4 < 57344) { s = taw2; d = taw2b; off = i4 - 53248; }
    else if (i4 < 61440) { s = maw2; d = maw2b; off = i4 - 57344; }
    else { s = mkw2; d = mkw2b; off = i4 - 61440; }
  }
  float4 v = *(const float4*)(s + off * 4);
  d[off * 4 + 0] = f2bf(v.x);
  d[off * 4 + 1] = f2bf(v.y);
  d[off * 4 + 2] = f2bf(v.z);
  d[off * 4 + 3] = f2bf(v.w);
}

// ---------------- Batched MFMA GEMM: C[z] = A[z] * W[z]^T -------------------
// 128x64 tile, 4 waves each owning 32 rows (2 M-frags x 4 N-frags = 8 accs,
// 16 MFMA per 64-K step/wave). Up to 6 GEMMs batched by blockIdx.z.
struct GemmBatch {
  const bf16* A[6]; const bf16* W[6];
  float* Cf[6]; bf16* Cb[6];
  int N[6]; int actN[6];
};

__global__ __launch_bounds__(256) void gemm_batch_kernel(GemmBatch gb, int K) {
  __shared__ __align__(16) bf16 As[128][72];  // padded rows: conflict-free reads
  __shared__ __align__(16) bf16 Ws[64][72];
  int z = blockIdx.z;
  int Nz = gb.N[z];
  int n0 = blockIdx.x << 6;
  if (n0 >= Nz) return;
  int m0 = blockIdx.y << 7;
  int actN = gb.actN[z];
  const bf16* A = gb.A[z];
  const bf16* W = gb.W[z];
  float* Cf = gb.Cf[z];
  bf16* Cb = gb.Cb[z];
  int tid = threadIdx.x;
  int arow = tid >> 1, acol = (tid & 1) << 5;   // A: 2 threads/row, 32 cols each
  int wrow = tid >> 2, wcol = (tid & 3) << 4;   // W: 4 threads/row, 16 cols each
  int wv = tid >> 6, lane = tid & 63;
  int fr = lane & 15, fq = lane >> 4;
  bool wok = (n0 + wrow) < Nz;
  const bf16* Ap = A + (long)(m0 + arow) * K + acol;
  const bf16* Wp = W + (long)(n0 + wrow) * K + wcol;
  short8 zz = {0, 0, 0, 0, 0, 0, 0, 0};
  f32x4 a00 = {0.f, 0.f, 0.f, 0.f};
  f32x4 a01 = a00, a02 = a00, a03 = a00, a10 = a00, a11 = a00, a12 = a00, a13 = a00;
  for (int k0 = 0; k0 < K; k0 += 64) {
    *(short8*)&As[arow][acol] = *(const short8*)(Ap + k0);
    *(short8*)&As[arow][acol + 8] = *(const short8*)(Ap + k0 + 8);
    *(short8*)&As[arow][acol + 16] = *(const short8*)(Ap + k0 + 16);
    *(short8*)&As[arow][acol + 24] = *(const short8*)(Ap + k0 + 24);
    *(short8*)&Ws[wrow][wcol] = wok ? *(const short8*)(Wp + k0) : zz;
    *(short8*)&Ws[wrow][wcol + 8] = wok ? *(const short8*)(Wp + k0 + 8) : zz;
    __syncthreads();
#pragma unroll
    for (int kk = 0; kk < 2; kk++) {
      int ko = (fq << 3) + (kk << 5);
      short8 af0 = *(const short8*)&As[(wv << 5) + fr][ko];
      short8 af1 = *(const short8*)&As[(wv << 5) + 16 + fr][ko];
      short8 b0 = *(const short8*)&Ws[fr][ko];
      short8 b1 = *(const short8*)&Ws[16 + fr][ko];
      short8 b2 = *(const short8*)&Ws[32 + fr][ko];
      short8 b3 = *(const short8*)&Ws[48 + fr][ko];
      a00 = __builtin_amdgcn_mfma_f32_16x16x32_bf16(af0, b0, a00, 0, 0, 0);
      a01 = __builtin_amdgcn_mfma_f32_16x16x32_bf16(af0, b1, a01, 0, 0, 0);
      a02 = __builtin_amdgcn_mfma_f32_16x16x32_bf16(af0, b2, a02, 0, 0, 0);
      a03 = __builtin_amdgcn_mfma_f32_16x16x32_bf16(af0, b3, a03, 0, 0, 0);
      a10 = __builtin_amdgcn_mfma_f32_16x16x32_bf16(af1, b0, a10, 0, 0, 0);
      a11 = __builtin_amdgcn_mfma_f32_16x16x32_bf16(af1, b1, a11, 0, 0, 0);
      a12 = __builtin_amdgcn_mfma_f32_16x16x32_bf16(af1, b2, a12, 0, 0, 0);
      a13 = __builtin_amdgcn_mfma_f32_16x16x32_bf16(af1, b3, a13, 0, 0, 0);
    }
    __syncthreads();
  }
  int ocol = n0 + fr;
  int orow0 = m0 + (wv << 5) + (fq << 2);
#define WRB(accv, mf, nt) { int col = ocol + ((nt) << 4); if (col < Nz) { \
    _Pragma("unroll") for (int r = 0; r < 4; r++) { \
      float vvv = accv[r]; if (col < actN) vvv = tanhf(vvv); \
      long oi = (long)(orow0 + ((mf) << 4) + r) * Nz + col; \
      if (Cb) Cb[oi] = f2bf(vvv); else Cf[oi] = vvv; } } }
  WRB(a00, 0, 0) WRB(a01, 0, 1) WRB(a02, 0, 2) WRB(a03, 0, 3)
  WRB(a10, 1, 0) WRB(a11, 1, 1) WRB(a12, 1, 2) WRB(a13, 1, 3)
#undef WRB
}

// ---------------- mix GEMM with fused token-shift A-staging -----------------
// A = xxx = x + (xprev - x)*tmx computed on the fly from f32 x (shift_kernel
// deleted; saves its launch + 8MB write + 16MB read). N=128, K=1024, tanh all.
__global__ __launch_bounds__(256) void gemm_mix_kernel(
    const float* __restrict__ x, const float* __restrict__ tmx,
    const bf16* __restrict__ W, float* __restrict__ Cf) {
  __shared__ __align__(16) bf16 As[128][72];
  __shared__ __align__(16) bf16 Ws[64][72];
  const int K = 1024;
  int n0 = blockIdx.x << 6;
  int m0 = blockIdx.y << 7;
  int tid = threadIdx.x;
  int arow = tid >> 1, acol = (tid & 1) << 5;
  int wrow = tid >> 2, wcol = (tid & 3) << 4;
  int wv = tid >> 6, lane = tid & 63;
  int fr = lane & 15, fq = lane >> 4;
  int grow = m0 + arow;
  int t = grow & (T_ - 1);
  const float* xp = x + (long)grow * C_ + acol;
  const bf16* Wp = W + (long)(n0 + wrow) * K + wcol;
  f32x4 a00 = {0.f, 0.f, 0.f, 0.f};
  f32x4 a01 = a00, a02 = a00, a03 = a00, a10 = a00, a11 = a00, a12 = a00, a13 = a00;
  for (int k0 = 0; k0 < K; k0 += 64) {
#pragma unroll
    for (int jj = 0; jj < 4; jj++) {   // 8 cols per jj
      int co = k0 + (jj << 3);
      float4 c0 = *(const float4*)(xp + co);
      float4 c1 = *(const float4*)(xp + co + 4);
      float4 q0 = {0.f, 0.f, 0.f, 0.f}, q1 = q0;
      if (t > 0) {
        q0 = *(const float4*)(xp + co - C_);
        q1 = *(const float4*)(xp + co + 4 - C_);
      }
      float4 m0v = *(const float4*)(tmx + co + acol);
      float4 m1v = *(const float4*)(tmx + co + acol + 4);
      short8 sv;
      sv[0] = bfbits(fmaf(q0.x - c0.x, m0v.x, c0.x));
      sv[1] = bfbits(fmaf(q0.y - c0.y, m0v.y, c0.y));
      sv[2] = bfbits(fmaf(q0.z - c0.z, m0v.z, c0.z));
      sv[3] = bfbits(fmaf(q0.w - c0.w, m0v.w, c0.w));
      sv[4] = bfbits(fmaf(q1.x - c1.x, m1v.x, c1.x));
      sv[5] = bfbits(fmaf(q1.y - c1.y, m1v.y, c1.y));
      sv[6] = bfbits(fmaf(q1.z - c1.z, m1v.z, c1.z));
      sv[7] = bfbits(fmaf(q1.w - c1.w, m1v.w, c1.w));
      *(short8*)&As[arow][acol + (jj << 3)] = sv;
    }
    *(short8*)&Ws[wrow][wcol] = *(const short8*)(Wp + k0);
    *(short8*)&Ws[wrow][wcol + 8] = *(const short8*)(Wp + k0 + 8);
    __syncthreads();
#pragma unroll
    for (int kk = 0; kk < 2; kk++) {
      int ko = (fq << 3) + (kk << 5);
      short8 af0 = *(const short8*)&As[(wv << 5) + fr][ko];
      short8 af1 = *(const short8*)&As[(wv << 5) + 16 + fr][ko];
      short8 b0 = *(const short8*)&Ws[fr][ko];
      short8 b1 = *(const short8*)&Ws[16 + fr][ko];
      short8 b2 = *(const short8*)&Ws[32 + fr][ko];
      short8 b3 = *(const short8*)&Ws[48 + fr][ko];
      a00 = __builtin_amdgcn_mfma_f32_16x16x32_bf16(af0, b0, a00, 0, 0, 0);
      a01 = __builtin_amdgcn_mfma_f32_16x16x32_bf16(af0, b1, a01, 0, 0, 0);
      a02 = __builtin_amdgcn_mfma_f32_16x16x32_bf16(af0, b2, a02, 0, 0, 0);
      a03 = __builtin_amdgcn_mfma_f32_16x16x32_bf16(af0, b3, a03, 0, 0, 0);
      a10 = __builtin_amdgcn_mfma_f32_16x16x32_bf16(af1, b0, a10, 0, 0, 0);
      a11 = __builtin_amdgcn_mfma_f32_16x16x32_bf16(af1, b1, a11, 0, 0, 0);
      a12 = __builtin_amdgcn_mfma_f32_16x16x32_bf16(af1, b2, a12, 0, 0, 0);
      a13 = __builtin_amdgcn_mfma_f32_16x16x32_bf16(af1, b3, a13, 0, 0, 0);
    }
    __syncthreads();
  }
  const int Nz = 128;
  int ocol = n0 + fr;
  int orow0 = m0 + (wv << 5) + (fq << 2);
#define WRM(accv, mf, nt) { int col = ocol + ((nt) << 4); \
    _Pragma("unroll") for (int r = 0; r < 4; r++) { \
      long oi = (long)(orow0 + ((mf) << 4) + r) * Nz + col; \
      Cf[oi] = tanhf(accv[r]); } }
  WRM(a00, 0, 0) WRM(a01, 0, 1) WRM(a02, 0, 2) WRM(a03, 0, 3)
  WRM(a10, 1, 0) WRM(a11, 1, 1) WRM(a12, 1, 2) WRM(a13, 1, 3)
#undef WRM
}

// ---------------- K3: deltas + build xrg/xwa/xk/xv (bf16 out) ---------------
// xx = xprev - x recomputed inline from x (L2-hot); shift kernel removed.
__global__ __launch_bounds__(256) void mix4_kernel(
    const float* __restrict__ x,
    const float* __restrict__ mix, const float* __restrict__ tmaa,
    const bf16* __restrict__ w2b,
    bf16* __restrict__ xrg, bf16* __restrict__ xwa,
    bf16* __restrict__ xk, bf16* __restrict__ xv) {
  int m = blockIdx.x;
  int t = m & (T_ - 1);
  int tid = threadIdx.x;
  __shared__ float mrow[128];
  if (tid < 128) mrow[tid] = mix[(long)m * 128 + tid];
  __syncthreads();
#pragma unroll
  for (int cc = 0; cc < 4; cc++) {
    int c = tid + (cc << 8);
    long off = (long)m * C_ + c;
    float xb = x[off];
    float xxv = ((t > 0) ? x[off - C_] : 0.0f) - xb;
    float res[4];
#pragma unroll
    for (int f = 0; f < 4; f++) {
      const short8* wp = (const short8*)(w2b + (((long)f * C_ + c) << 5));
      float dl = 0.f;
#pragma unroll
      for (int d8 = 0; d8 < 4; d8++) {
        short8 u = wp[d8];
        int db = (f << 5) + (d8 << 3);
#pragma unroll
        for (int e = 0; e < 8; e++) dl += mrow[db + e] * bs2f(u[e]);
      }
      res[f] = xb + xxv * (tmaa[f * C_ + c] + dl);
    }
    xrg[off] = f2bf(res[0]); xwa[off] = f2bf(res[1]);
    xk[off] = f2bf(res[2]); xv[off] = f2bf(res[3]);
  }
}

// ---------------- K5: stage-2 small GEMMs + gates + per-head kk norm --------
__global__ __launch_bounds__(256) void fuse2_kernel(
    const float* __restrict__ kraw, const float* __restrict__ out1,
    const float* __restrict__ out2,
    const bf16* __restrict__ dw2, const bf16* __restrict__ kkw2,
    const bf16* __restrict__ aw2, const bf16* __restrict__ maw2,
    const bf16* __restrict__ mkw2,
    const float* __restrict__ tdec, const float* __restrict__ taa,
    const float* __restrict__ tma, const float* __restrict__ tmk,
    float* __restrict__ ew, float* __restrict__ kfin,
    float* __restrict__ kkn, float* __restrict__ bbo) {
  int m = blockIdx.x, tid = threadIdx.x;
  __shared__ float w1r[64], kk1r[16], a1r[16], ma1r[16], mk1r[16];
  if (tid < 64) w1r[tid] = out2[(long)m * 96 + tid];
  else if (tid < 80) kk1r[tid - 64] = out1[(long)m * 32 + (tid - 64)];
  else if (tid < 96) a1r[tid - 80] = out2[(long)m * 96 + 64 + (tid - 80)];
  else if (tid < 112) ma1r[tid - 96] = out2[(long)m * 96 + 80 + (tid - 96)];
  else if (tid < 128) mk1r[tid - 112] = out1[(long)m * 32 + 16 + (tid - 112)];
  __syncthreads();
  float kkp[4], av[4], wv[4], kr[4], mkv[4];
  float sumsq = 0.f;
#pragma unroll
  for (int j = 0; j < 4; j++) {
    int c = (tid << 2) + j;
    long off = (long)m * C_ + c;
    float wd = 0.f;
    const short8* dp = (const short8*)(dw2 + ((long)c << 6));
#pragma unroll
    for (int d8 = 0; d8 < 8; d8++) {
      short8 u = dp[d8];
      int db = d8 << 3;
#pragma unroll
      for (int e = 0; e < 8; e++) wd += w1r[db + e] * bs2f(u[e]);
    }
    float w = -softplusf_(-(tdec[c] + wd)) - 0.5f;
    wv[j] = w;
    float kd = 0.f, ad = 0.f, mad = 0.f, mkd = 0.f;
    const short8* kp = (const short8*)(kkw2 + ((long)c << 4));
    const short8* ap = (const short8*)(aw2 + ((long)c << 4));
    const short8* mp = (const short8*)(maw2 + ((long)c << 4));
    const short8* qp = (const short8*)(mkw2 + ((long)c << 4));
#pragma unroll
    for (int d8 = 0; d8 < 2; d8++) {
      short8 u1 = kp[d8], u2 = ap[d8], u3 = mp[d8], u4 = qp[d8];
      int db = d8 << 3;
#pragma unroll
      for (int e = 0; e < 8; e++) {
        kd += kk1r[db + e] * bs2f(u1[e]);
        ad += a1r[db + e] * bs2f(u2[e]);
        mad += ma1r[db + e] * bs2f(u3[e]);
        mkd += mk1r[db + e] * bs2f(u4[e]);
      }
    }
    float krw = kraw[off];
    float kkpre = krw + kd;
    kkp[j] = kkpre;
    sumsq += kkpre * kkpre;
    float a = sigmoidf_(taa[c] + ad);
    av[j] = a;
    float ma = sigmoidf_(tma[c] + mad);
    float mk = sigmoidf_(tmk[c] + mkd);
    mkv[j] = mk;
    kr[j] = krw * (ma + a * (1.f - ma));
  }
  sumsq += __shfl_xor(sumsq, 1);
  sumsq += __shfl_xor(sumsq, 2);
  sumsq += __shfl_xor(sumsq, 4);
  sumsq += __shfl_xor(sumsq, 8);
  float rn = 1.0f / fmaxf(sqrtf(sumsq), 1e-12f);
#pragma unroll
  for (int j = 0; j < 4; j++) {
    int c = (tid << 2) + j;
    long off = (long)m * C_ + c;
    float kknv = kkp[j] * rn;
    kkn[off] = kknv;
    bbo[off] = -kknv * av[j];
    ew[off] = expf(wv[j]);
    kfin[off] = kr[j] * expf(wv[j] * mkv[j]);
  }
}

// ---------------- K6: RWKV-7 scan, 128 blocks x 256 threads -----------------
// R3 structure (dbuf LDS, 3-set rotating register pipeline, sched_barrier).
// R7: y-reduction software-pipelined one token deep + qsum16x2 interleaves
// the sab chain of token t with the y chain of token t-1 (in-order issue made
// the y DPP chain serialize in front of token t+1 even though it's off the
// recurrence path). Store of y_{t-1} happens during token t; epilogue flushes
// the final token.
#define SCHUNK 16
#define NCHUNK (T_ / SCHUNK)
__global__ __launch_bounds__(256, 1) void scan_kernel(
    const float* __restrict__ rB, const float* __restrict__ ewB,
    const float* __restrict__ kB, const float* __restrict__ vB,
    const float* __restrict__ kkB, const float* __restrict__ bbB,
    float* __restrict__ yB) {
  __shared__ __align__(16) float lds[2][6][SCHUNK * 64];
  int bid = blockIdx.x;          // 0..127
  int bh = bid >> 2, rg = bid & 3;
  int b = bh >> 4, h = bh & 15;
  int tid = threadIdx.x;
  int wave = tid >> 6, lane = tid & 63;
  int g = lane >> 4, q = lane & 15;
  int row = (rg << 4) + (wave << 2) + g;   // this lane's single row
  int kq = q << 2;                         // 4 keys: kq..kq+3
  const long base = ((long)b * T_) * C_ + (h << 6);
  const float* s0 = kkB + base;
  const float* s1 = ewB + base;
  const float* s2 = kB + base;
  const float* s3 = bbB + base;
  const float* s4 = rB + base;
  const float* s5 = vB + base;
  int stok = tid >> 4;           // staging token within chunk (0..15)
  int spc = (tid & 15) << 2;     // float offset within token row
  int lo = (stok << 6) + spc;    // LDS float offset
  float4 rb0, rb1, rb2, rb3, rb4, rb5;
  auto loadc = [&](int c) {
    long go = (long)((c << 4) + stok) * C_ + spc;
    rb0 = *(const float4*)(s0 + go);
    rb1 = *(const float4*)(s1 + go);
    rb2 = *(const float4*)(s2 + go);
    rb3 = *(const float4*)(s3 + go);
    rb4 = *(const float4*)(s4 + go);
    rb5 = *(const float4*)(s5 + go);
  };
  auto stage = [&](int buf) {
    *(float4*)&lds[buf][0][lo] = rb0;
    *(float4*)&lds[buf][1][lo] = rb1;
    *(float4*)&lds[buf][2][lo] = rb2;
    *(float4*)&lds[buf][3][lo] = rb3;
    *(float4*)&lds[buf][4][lo] = rb4;
    *(float4*)&lds[buf][5][lo] = rb5;
  };
  float S0 = 0.f, S1 = 0.f, S2 = 0.f, S3 = 0.f;
  float ypv = 0.f;               // pending y-partial of previous token
  // 3 rotating prefetch sets (static names; token tt uses set tt%3)
  float4 Q0kk, Q0ew, Q0k, Q0bb, Q0r; float Q0v;
  float4 Q1kk, Q1ew, Q1k, Q1bb, Q1r; float Q1v;
  float4 Q2kk, Q2ew, Q2k, Q2bb, Q2r; float Q2v;

#define PF(i, tt) { int tb_ = ((tt) << 6); \
    Q##i##kk = *(const float4*)&lds[cur][0][tb_ + kq]; \
    Q##i##ew = *(const float4*)&lds[cur][1][tb_ + kq]; \
    Q##i##k  = *(const float4*)&lds[cur][2][tb_ + kq]; \
    Q##i##bb = *(const float4*)&lds[cur][3][tb_ + kq]; \
    Q##i##r  = *(const float4*)&lds[cur][4][tb_ + kq]; \
    Q##i##v  = lds[cur][5][tb_ + row]; }
#define SBAR __builtin_amdgcn_sched_barrier(0x7)
// FIRSTT: compile-time flag, true only for the tt==0 call in each chunk; the
// very first token globally (c==0, tt==0) has no pending y to store.
#define ST(i, gtok, FIRSTT) { \
    float p_ = fmaf(S1, Q##i##kk.y, S0 * Q##i##kk.x) + \
               fmaf(S3, Q##i##kk.w, S2 * Q##i##kk.z); \
    float yo_ = ypv; \
    qsum16x2(p_, yo_); \
    if (q == 0 && !((FIRSTT) && c == 0)) \
      yB[base + (long)((gtok) - 1) * C_ + row] = yo_; \
    float n0 = fmaf(S0, Q##i##ew.x, Q##i##v * Q##i##k.x); \
    float n1 = fmaf(S1, Q##i##ew.y, Q##i##v * Q##i##k.y); \
    float n2 = fmaf(S2, Q##i##ew.z, Q##i##v * Q##i##k.z); \
    float n3 = fmaf(S3, Q##i##ew.w, Q##i##v * Q##i##k.w); \
    S0 = fmaf(p_, Q##i##bb.x, n0); \
    S1 = fmaf(p_, Q##i##bb.y, n1); \
    S2 = fmaf(p_, Q##i##bb.z, n2); \
    S3 = fmaf(p_, Q##i##bb.w, n3); \
    ypv = fmaf(S1, Q##i##r.y, S0 * Q##i##r.x) + \
          fmaf(S3, Q##i##r.w, S2 * Q##i##r.z); }

  // prologue: chunk 0 -> buf0; chunk 1 loaded into regs
  loadc(0);
  stage(0);
  loadc(1);
  __syncthreads();
  int cur = 0;
  for (int c = 0; c < NCHUNK; c++) {
    int t0 = c << 4;
    // prefetch tokens 0,1 of this chunk (reads queue before the stage writes)
    PF(0, 0); PF(1, 1);
    if (c + 1 < NCHUNK) stage(cur ^ 1);   // regs hold chunk c+1
    if (c + 2 < NCHUNK) loadc(c + 2);     // issue global loads, 16-token cover
    SBAR;
    PF(2, 2);  SBAR; ST(0, t0 + 0, true);
    PF(0, 3);  SBAR; ST(1, t0 + 1, false);
    PF(1, 4);  SBAR; ST(2, t0 + 2, false);
    PF(2, 5);  SBAR; ST(0, t0 + 3, false);
    PF(0, 6);  SBAR; ST(1, t0 + 4, false);
    PF(1, 7);  SBAR; ST(2, t0 + 5, false);
    PF(2, 8);  SBAR; ST(0, t0 + 6, false);
    PF(0, 9);  SBAR; ST(1, t0 + 7, false);
    PF(1, 10); SBAR; ST(2, t0 + 8, false);
    PF(2, 11); SBAR; ST(0, t0 + 9, false);
    PF(0, 12); SBAR; ST(1, t0 + 10, false);
    PF(1, 13); SBAR; ST(2, t0 + 11, false);
    PF(2, 14); SBAR; ST(0, t0 + 12, false);
    PF(0, 15); SBAR; ST(1, t0 + 13, false);
    ST(2, t0 + 14, false);
    ST(0, t0 + 15, false);
    __syncthreads();
    cur ^= 1;
  }
  // epilogue: flush the last token's y
  {
    float yo = qsum16(ypv);
    if (q == 0) yB[base + (long)(T_ - 1) * C_ + row] = yo;
  }
#undef PF
#undef SBAR
#undef ST
}

// ---------------- K7: GroupNorm + bonus + gate (bf16 out) -------------------
__global__ __launch_bounds__(256) void gnout_kernel(
    const float* __restrict__ y, const float* __restrict__ r,
    const float* __restrict__ kf, const float* __restrict__ v,
    const float* __restrict__ g,
    const float* __restrict__ lnw, const float* __restrict__ lnb,
    const float* __restrict__ fa, bf16* __restrict__ z) {
  int tid = threadIdx.x;
  int w = tid >> 6, lane = tid & 63;
  int gi = (blockIdx.x << 2) + w;  // (b*T+t)*H + h
  int h = gi & 15, mt = gi >> 4;
  long off = (long)mt * C_ + (h << 6) + lane;
  float yv = y[off];
  float s = yv;
  s += __shfl_xor(s, 1); s += __shfl_xor(s, 2); s += __shfl_xor(s, 4);
  s += __shfl_xor(s, 8); s += __shfl_xor(s, 16); s += __shfl_xor(s, 32);
  float mu = s * (1.0f / 64.0f);
  float d = yv - mu;
  float s2 = d * d;
  s2 += __shfl_xor(s2, 1); s2 += __shfl_xor(s2, 2); s2 += __shfl_xor(s2, 4);
  s2 += __shfl_xor(s2, 8); s2 += __shfl_xor(s2, 16); s2 += __shfl_xor(s2, 32);
  float var = s2 * (1.0f / 64.0f);
  int hc = (h << 6) + lane;
  float dot = r[off] * kf[off] * fa[hc];
  dot += __shfl_xor(dot, 1); dot += __shfl_xor(dot, 2); dot += __shfl_xor(dot, 4);
  dot += __shfl_xor(dot, 8); dot += __shfl_xor(dot, 16); dot += __shfl_xor(dot, 32);
  float yn = d * rsqrtf(var + 0.00064f) * lnw[hc] + lnb[hc];
  z[off] = f2bf((yn + dot * v[off]) * g[off]);
}

extern "C" void kernel_launch(void* const* d_in, const int* in_sizes, int n_in,
                              void* d_out, int out_size, void* d_ws, size_t ws_size,
                              hipStream_t stream) {
  const float* x = (const float*)d_in[0];
  const float* tmx = (const float*)d_in[1];
  const float* tmaa = (const float*)d_in[2];
  const float* tmw1 = (const float*)d_in[3];
  const float* tmw2 = (const float*)d_in[4];
  const float* tdec = (const float*)d_in[5];
  const float* tdw1 = (const float*)d_in[6];
  const float* tdw2 = (const float*)d_in[7];
  const float* taa5 = (const float*)d_in[8];
  const float* taw1 = (const float*)d_in[9];
  const float* taw2 = (const float*)d_in[10];
  const float* tkw1 = (const float*)d_in[11];
  const float* tkw2 = (const float*)d_in[12];
  const float* gw1 = (const float*)d_in[13];
  const float* gw2 = (const float*)d_in[14];
  const float* tmia = (const float*)d_in[15];
  const float* maw1 = (const float*)d_in[16];
  const float* maw2 = (const float*)d_in[17];
  const float* tmik = (const float*)d_in[18];
  const float* mkw1 = (const float*)d_in[19];
  const float* mkw2 = (const float*)d_in[20];
  const float* wrec = (const float*)d_in[21];
  const float* wkey = (const float*)d_in[22];
  const float* wval = (const float*)d_in[23];
  const float* wout = (const float*)d_in[24];
  const float* lnw = (const float*)d_in[25];
  const float* lnb = (const float*)d_in[26];
  const float* faaa = (const float*)d_in[27];

  const long MT = 2048, CC = 1024;
  char* base = (char*)d_ws;
  float* xx = (float*)base;    base += MT * CC * 4;   // y lives here
  bf16* xxxb = (bf16*)base;    base += MT * CC * 2;   // unused (kept for layout)
  bf16* xrgb = (bf16*)base;    base += MT * CC * 2;   // ┐ kfin overlays (8MB)
  bf16* xwab = (bf16*)base;    base += MT * CC * 2;   // ┘
  bf16* xkb = (bf16*)base;     base += MT * CC * 2;   // ┐ kkn overlays (8MB)
  bf16* xvb = (bf16*)base;     base += MT * CC * 2;   // ┘
  float* rr = (float*)base;    base += MT * CC * 4;
  float* kraw = (float*)base;  base += MT * CC * 4;   // also ew
  float* vv = (float*)base;    base += MT * CC * 4;
  float* gg = (float*)base;    base += MT * CC * 4;
  float* bbo = (float*)base;   base += MT * CC * 4;
  float* mix = (float*)base;   base += MT * 128 * 4;
  bf16* g1b = (bf16*)base;     base += MT * 128 * 2;
  float* out1 = (float*)base;  base += MT * 32 * 4;   // [kk1|mk1]
  float* out2 = (float*)base;  base += MT * 96 * 4;   // [w1|a1|ma1]
  bf16* zb = (bf16*)base;      base += MT * CC * 2;
  bf16* tmw1b = (bf16*)base;   base += 128 * CC * 2;
  bf16* wrecb = (bf16*)base;   base += CC * CC * 2;
  bf16* gw1b = (bf16*)base;    base += 128 * CC * 2;
  bf16* gw2b = (bf16*)base;    base += CC * 128 * 2;
  bf16* wkeyb = (bf16*)base;   base += CC * CC * 2;
  bf16* wvalb = (bf16*)base;   base += CC * CC * 2;
  bf16* woutb = (bf16*)base;   base += CC * CC * 2;
  bf16* wskb = (bf16*)base;    base += 32 * CC * 2;
  bf16* wswab = (bf16*)base;   base += 96 * CC * 2;
  bf16* tmw2b = (bf16*)base;   base += 4 * CC * 32 * 2;
  bf16* tdw2b = (bf16*)base;   base += CC * 64 * 2;
  bf16* tkw2b = (bf16*)base;   base += CC * 16 * 2;
  bf16* taw2b = (bf16*)base;   base += CC * 16 * 2;
  bf16* maw2b = (bf16*)base;   base += CC * 16 * 2;
  bf16* mkw2b = (bf16*)base;   base += CC * 16 * 2;
  // aliases (dead-buffer reuse, verified non-overlapping in time):
  float* ew = kraw;            // fuse2 reads kraw then writes ew at same offs
  float* kfin = (float*)xrgb;  // xrg/xwa bf16 dead before fuse2
  float* kkn = (float*)xkb;    // xk/xv bf16 dead before fuse2
  float* y = xx;               // xx region reused for y
  (void)xxxb;

  cvt_all_kernel<<<4864, 256, 0, stream>>>(
      tmw1, wrec, gw1, gw2, wkey, wval, wout,
      tmw1b, wrecb, gw1b, gw2b, wkeyb, wvalb, woutb,
      tkw1, mkw1, tdw1, taw1, maw1, wskb, wswab,
      tmw2, tdw2, tkw2, taw2, maw2, mkw2,
      tmw2b, tdw2b, tkw2b, taw2b, maw2b, mkw2b);

  // mix GEMM with fused token-shift A-staging (shift kernel removed)
  gemm_mix_kernel<<<dim3(2, 16), 256, 0, stream>>>(x, tmx, tmw1b, mix);
  mix4_kernel<<<2048, 256, 0, stream>>>(x, mix, tmaa, tmw2b,
                                        xrgb, xwab, xkb, xvb);
  // 6 independent K=1024 GEMMs, one launch
  {
    GemmBatch gb = {};
    gb.A[0] = xrgb; gb.W[0] = wrecb; gb.Cf[0] = rr;   gb.Cb[0] = nullptr; gb.N[0] = 1024; gb.actN[0] = 0;
    gb.A[1] = xrgb; gb.W[1] = gw1b;  gb.Cf[1] = nullptr; gb.Cb[1] = g1b;  gb.N[1] = 128;  gb.actN[1] = 128;
    gb.A[2] = xkb;  gb.W[2] = wkeyb; gb.Cf[2] = kraw; gb.Cb[2] = nullptr; gb.N[2] = 1024; gb.actN[2] = 0;
    gb.A[3] = xkb;  gb.W[3] = wskb;  gb.Cf[3] = out1; gb.Cb[3] = nullptr; gb.N[3] = 32;   gb.actN[3] = 16;
    gb.A[4] = xvb;  gb.W[4] = wvalb; gb.Cf[4] = vv;   gb.Cb[4] = nullptr; gb.N[4] = 1024; gb.actN[4] = 0;
    gb.A[5] = xwab; gb.W[5] = wswab; gb.Cf[5] = out2; gb.Cb[5] = nullptr; gb.N[5] = 96;   gb.actN[5] = 64;
    gemm_batch_kernel<<<dim3(16, 16, 6), 256, 0, stream>>>(gb, 1024);
  }
  // gg GEMM: (2048x128)x(1024x128)^T
  {
    GemmBatch gb = {};
    gb.A[0] = g1b; gb.W[0] = gw2b; gb.Cf[0] = gg; gb.Cb[0] = nullptr;
    gb.N[0] = 1024; gb.actN[0] = 0;
    gemm_batch_kernel<<<dim3(16, 16, 1), 256, 0, stream>>>(gb, 128);
  }
  fuse2_kernel<<<2048, 256, 0, stream>>>(kraw, out1, out2,
                                         tdw2b, tkw2b, taw2b, maw2b, mkw2b,
                                         tdec, taa5, tmia, tmik,
                                         ew, kfin, kkn, bbo);
  scan_kernel<<<128, 256, 0, stream>>>(rr, ew, kfin, vv, kkn, bbo, y);
  gnout_kernel<<<8192, 256, 0, stream>>>(y, rr, kfin, vv, gg, lnw, lnb, faaa, zb);
  // output GEMM: (2048x1024)x(1024x1024)^T
  {
    GemmBatch gb = {};
    gb.A[0] = zb; gb.W[0] = woutb; gb.Cf[0] = (float*)d_out; gb.Cb[0] = nullptr;
    gb.N[0] = 1024; gb.actN[0] = 0;
    gemm_batch_kernel<<<dim3(16, 16, 1), 256, 0, stream>>>(gb, 1024);
  }
}

// Round 8
// 522.670 us; speedup vs baseline: 1.2508x; 1.0430x over previous
//
#include <hip/hip_runtime.h>
#include <hip/hip_bf16.h>

typedef __hip_bfloat16 bf16;

#define B_ 2
#define T_ 1024
#define C_ 1024
#define H_ 16
#define N_ 64

using short4v = __attribute__((ext_vector_type(4))) short;
using short8 = __attribute__((ext_vector_type(8))) short;
using f32x4 = __attribute__((ext_vector_type(4))) float;

__device__ __forceinline__ float us2f(unsigned short u) {
  return __uint_as_float(((unsigned int)u) << 16);
}
__device__ __forceinline__ float bs2f(short s) {
  return __uint_as_float(((unsigned int)(unsigned short)s) << 16);
}
__device__ __forceinline__ bf16 f2bf(float f) { return __float2bfloat16(f); }
__device__ __forceinline__ short bfbits(float f) {
  bf16 h = __float2bfloat16(f);
  return *reinterpret_cast<short*>(&h);
}
__device__ __forceinline__ float sigmoidf_(float x) { return 1.0f / (1.0f + expf(-x)); }
__device__ __forceinline__ float softplusf_(float x) {
  return fmaxf(x, 0.0f) + log1pf(expf(-fabsf(x)));
}
// Full 16-lane-row sum, all lanes receive the result. Pure-VALU DPP.
__device__ __forceinline__ float qsum16(float x) {
  int a = __builtin_amdgcn_update_dpp(0, __float_as_int(x), 0xB1, 0xF, 0xF, true);
  x += __int_as_float(a);
  int b = __builtin_amdgcn_update_dpp(0, __float_as_int(x), 0x4E, 0xF, 0xF, true);
  x += __int_as_float(b);
  int c = __builtin_amdgcn_update_dpp(0, __float_as_int(x), 0x124, 0xF, 0xF, true);
  x += __int_as_float(c);
  int d = __builtin_amdgcn_update_dpp(0, __float_as_int(x), 0x128, 0xF, 0xF, true);
  x += __int_as_float(d);
  return x;
}
// Two interleaved 16-lane-row sums (overlaps token t's sab chain with token
// t-1's y chain; see scan_kernel comment).
__device__ __forceinline__ void qsum16x2(float& x, float& y) {
  int a0 = __builtin_amdgcn_update_dpp(0, __float_as_int(x), 0xB1, 0xF, 0xF, true);
  int b0 = __builtin_amdgcn_update_dpp(0, __float_as_int(y), 0xB1, 0xF, 0xF, true);
  x += __int_as_float(a0); y += __int_as_float(b0);
  int a1 = __builtin_amdgcn_update_dpp(0, __float_as_int(x), 0x4E, 0xF, 0xF, true);
  int b1 = __builtin_amdgcn_update_dpp(0, __float_as_int(y), 0x4E, 0xF, 0xF, true);
  x += __int_as_float(a1); y += __int_as_float(b1);
  int a2 = __builtin_amdgcn_update_dpp(0, __float_as_int(x), 0x124, 0xF, 0xF, true);
  int b2 = __builtin_amdgcn_update_dpp(0, __float_as_int(y), 0x124, 0xF, 0xF, true);
  x += __int_as_float(a2); y += __int_as_float(b2);
  int a3 = __builtin_amdgcn_update_dpp(0, __float_as_int(x), 0x128, 0xF, 0xF, true);
  int b3 = __builtin_amdgcn_update_dpp(0, __float_as_int(y), 0x128, 0xF, 0xF, true);
  x += __int_as_float(a3); y += __int_as_float(b3);
}

// ---------------- K0: ALL weight conversions + tmw2 expansion, one launch ---
// R8: tmw2 (4,C,32) is expanded to tmw2e (4096 x 128) bf16 with zero blocks:
// tmw2e[n][k] = (k>>5 == n>>10) ? tmw2[n*32 + (k&31)] : 0. This turns mix4's
// per-block 256KB weight re-read (512MB L2 storm + 23us VALU) into one MFMA
// GEMM: deltas[m][n] = sum_k mixb[m][k] * tmw2e[n][k].
__global__ __launch_bounds__(256) void cvt_all_kernel(
    const float* __restrict__ s0, const float* __restrict__ s1,
    const float* __restrict__ s2, const float* __restrict__ s3,
    const float* __restrict__ s4, const float* __restrict__ s5,
    const float* __restrict__ s6,
    bf16* __restrict__ d0, bf16* __restrict__ d1, bf16* __restrict__ d2,
    bf16* __restrict__ d3, bf16* __restrict__ d4, bf16* __restrict__ d5,
    bf16* __restrict__ d6,
    const float* __restrict__ tkw1, const float* __restrict__ mkw1,
    const float* __restrict__ tdw1, const float* __restrict__ taw1,
    const float* __restrict__ maw1,
    bf16* __restrict__ wsk, bf16* __restrict__ wswa,
    const float* __restrict__ tmw2, const float* __restrict__ tdw2,
    const float* __restrict__ tkw2, const float* __restrict__ taw2,
    const float* __restrict__ maw2, const float* __restrict__ mkw2,
    bf16* __restrict__ tmw2e, bf16* __restrict__ tdw2b,
    bf16* __restrict__ tkw2b, bf16* __restrict__ taw2b,
    bf16* __restrict__ maw2b, bf16* __restrict__ mkw2b) {
  long bidx = blockIdx.x;
  const float* s; bf16* d; long off;
  if (bidx < 4480) {                      // big weights
    long i4 = bidx * 256 + threadIdx.x;
    if (i4 < 32768) { s = s0; d = d0; off = i4; }
    else if (i4 < 294912) { s = s1; d = d1; off = i4 - 32768; }
    else if (i4 < 327680) { s = s2; d = d2; off = i4 - 294912; }
    else if (i4 < 360448) { s = s3; d = d3; off = i4 - 327680; }
    else if (i4 < 622592) { s = s4; d = d4; off = i4 - 360448; }
    else if (i4 < 884736) { s = s5; d = d5; off = i4 - 622592; }
    else { s = s6; d = d6; off = i4 - 884736; }
  } else if (bidx < 4608) {               // LoRA-1 packs
    long i4 = (bidx - 4480) * 256 + threadIdx.x;  // < 32768
    long so, dof;
    if (i4 < 4096) { s = tkw1; so = i4; d = wsk; dof = i4; }
    else if (i4 < 8192) { s = mkw1; so = i4 - 4096; d = wsk; dof = i4; }
    else if (i4 < 24576) { s = tdw1; so = i4 - 8192; d = wswa; dof = i4 - 8192; }
    else if (i4 < 28672) { s = taw1; so = i4 - 24576; d = wswa; dof = i4 - 8192; }
    else { s = maw1; so = i4 - 28672; d = wswa; dof = i4 - 8192; }
    float4 v = *(const float4*)(s + so * 4);
    d[dof * 4 + 0] = f2bf(v.x); d[dof * 4 + 1] = f2bf(v.y);
    d[dof * 4 + 2] = f2bf(v.z); d[dof * 4 + 3] = f2bf(v.w);
    return;
  } else if (bidx < 4736) {               // LoRA-2 packs (without tmw2)
    long i4 = (bidx - 4608) * 256 + threadIdx.x;  // < 32768
    if (i4 < 16384) { s = tdw2; d = tdw2b; off = i4; }
    else if (i4 < 20480) { s = tkw2; d = tkw2b; off = i4 - 16384; }
    else if (i4 < 24576) { s = taw2; d = taw2b; off = i4 - 20480; }
    else if (i4 < 28672) { s = maw2; d = maw2b; off = i4 - 24576; }
    else { s = mkw2; d = mkw2b; off = i4 - 28672; }
  } else {                                // tmw2e expansion (4096x128 bf16)
    long i4 = (bidx - 4736) * 256 + threadIdx.x;  // < 131072 (4-elem groups)
    long n = i4 >> 5;            // output row (f*1024 + c)
    int k0 = (int)(i4 & 31) << 2;  // k base within 128
    int f = (int)(n >> 10);
    float4 v = {0.f, 0.f, 0.f, 0.f};
    if ((k0 >> 5) == f) v = *(const float4*)(tmw2 + n * 32 + (k0 & 31));
    tmw2e[i4 * 4 + 0] = f2bf(v.x);
    tmw2e[i4 * 4 + 1] = f2bf(v.y);
    tmw2e[i4 * 4 + 2] = f2bf(v.z);
    tmw2e[i4 * 4 + 3] = f2bf(v.w);
    return;
  }
  float4 v = *(const float4*)(s + off * 4);
  d[off * 4 + 0] = f2bf(v.x);
  d[off * 4 + 1] = f2bf(v.y);
  d[off * 4 + 2] = f2bf(v.z);
  d[off * 4 + 3] = f2bf(v.w);
}

// ---------------- Batched MFMA GEMM: C[z] = A[z] * W[z]^T -------------------
// 128x64 tile, 4 waves each owning 32 rows (2 M-frags x 4 N-frags = 8 accs,
// 16 MFMA per 64-K step/wave). Up to 6 GEMMs batched by blockIdx.z.
struct GemmBatch {
  const bf16* A[6]; const bf16* W[6];
  float* Cf[6]; bf16* Cb[6];
  int N[6]; int actN[6];
};

__global__ __launch_bounds__(256) void gemm_batch_kernel(GemmBatch gb, int K) {
  __shared__ __align__(16) bf16 As[128][72];  // padded rows: conflict-free reads
  __shared__ __align__(16) bf16 Ws[64][72];
  int z = blockIdx.z;
  int Nz = gb.N[z];
  int n0 = blockIdx.x << 6;
  if (n0 >= Nz) return;
  int m0 = blockIdx.y << 7;
  int actN = gb.actN[z];
  const bf16* A = gb.A[z];
  const bf16* W = gb.W[z];
  float* Cf = gb.Cf[z];
  bf16* Cb = gb.Cb[z];
  int tid = threadIdx.x;
  int arow = tid >> 1, acol = (tid & 1) << 5;   // A: 2 threads/row, 32 cols each
  int wrow = tid >> 2, wcol = (tid & 3) << 4;   // W: 4 threads/row, 16 cols each
  int wv = tid >> 6, lane = tid & 63;
  int fr = lane & 15, fq = lane >> 4;
  bool wok = (n0 + wrow) < Nz;
  const bf16* Ap = A + (long)(m0 + arow) * K + acol;
  const bf16* Wp = W + (long)(n0 + wrow) * K + wcol;
  short8 zz = {0, 0, 0, 0, 0, 0, 0, 0};
  f32x4 a00 = {0.f, 0.f, 0.f, 0.f};
  f32x4 a01 = a00, a02 = a00, a03 = a00, a10 = a00, a11 = a00, a12 = a00, a13 = a00;
  for (int k0 = 0; k0 < K; k0 += 64) {
    *(short8*)&As[arow][acol] = *(const short8*)(Ap + k0);
    *(short8*)&As[arow][acol + 8] = *(const short8*)(Ap + k0 + 8);
    *(short8*)&As[arow][acol + 16] = *(const short8*)(Ap + k0 + 16);
    *(short8*)&As[arow][acol + 24] = *(const short8*)(Ap + k0 + 24);
    *(short8*)&Ws[wrow][wcol] = wok ? *(const short8*)(Wp + k0) : zz;
    *(short8*)&Ws[wrow][wcol + 8] = wok ? *(const short8*)(Wp + k0 + 8) : zz;
    __syncthreads();
#pragma unroll
    for (int kk = 0; kk < 2; kk++) {
      int ko = (fq << 3) + (kk << 5);
      short8 af0 = *(const short8*)&As[(wv << 5) + fr][ko];
      short8 af1 = *(const short8*)&As[(wv << 5) + 16 + fr][ko];
      short8 b0 = *(const short8*)&Ws[fr][ko];
      short8 b1 = *(const short8*)&Ws[16 + fr][ko];
      short8 b2 = *(const short8*)&Ws[32 + fr][ko];
      short8 b3 = *(const short8*)&Ws[48 + fr][ko];
      a00 = __builtin_amdgcn_mfma_f32_16x16x32_bf16(af0, b0, a00, 0, 0, 0);
      a01 = __builtin_amdgcn_mfma_f32_16x16x32_bf16(af0, b1, a01, 0, 0, 0);
      a02 = __builtin_amdgcn_mfma_f32_16x16x32_bf16(af0, b2, a02, 0, 0, 0);
      a03 = __builtin_amdgcn_mfma_f32_16x16x32_bf16(af0, b3, a03, 0, 0, 0);
      a10 = __builtin_amdgcn_mfma_f32_16x16x32_bf16(af1, b0, a10, 0, 0, 0);
      a11 = __builtin_amdgcn_mfma_f32_16x16x32_bf16(af1, b1, a11, 0, 0, 0);
      a12 = __builtin_amdgcn_mfma_f32_16x16x32_bf16(af1, b2, a12, 0, 0, 0);
      a13 = __builtin_amdgcn_mfma_f32_16x16x32_bf16(af1, b3, a13, 0, 0, 0);
    }
    __syncthreads();
  }
  int ocol = n0 + fr;
  int orow0 = m0 + (wv << 5) + (fq << 2);
#define WRB(accv, mf, nt) { int col = ocol + ((nt) << 4); if (col < Nz) { \
    _Pragma("unroll") for (int r = 0; r < 4; r++) { \
      float vvv = accv[r]; if (col < actN) vvv = tanhf(vvv); \
      long oi = (long)(orow0 + ((mf) << 4) + r) * Nz + col; \
      if (Cb) Cb[oi] = f2bf(vvv); else Cf[oi] = vvv; } } }
  WRB(a00, 0, 0) WRB(a01, 0, 1) WRB(a02, 0, 2) WRB(a03, 0, 3)
  WRB(a10, 1, 0) WRB(a11, 1, 1) WRB(a12, 1, 2) WRB(a13, 1, 3)
#undef WRB
}

// ---------------- mix GEMM with fused token-shift A-staging -----------------
// A = xxx = x + (xprev - x)*tmx computed on the fly from f32 x. N=128,
// K=1024, tanh all. R8: writes bf16 (mixb feeds the deltas GEMM directly).
__global__ __launch_bounds__(256) void gemm_mix_kernel(
    const float* __restrict__ x, const float* __restrict__ tmx,
    const bf16* __restrict__ W, bf16* __restrict__ Cb) {
  __shared__ __align__(16) bf16 As[128][72];
  __shared__ __align__(16) bf16 Ws[64][72];
  const int K = 1024;
  int n0 = blockIdx.x << 6;
  int m0 = blockIdx.y << 7;
  int tid = threadIdx.x;
  int arow = tid >> 1, acol = (tid & 1) << 5;
  int wrow = tid >> 2, wcol = (tid & 3) << 4;
  int wv = tid >> 6, lane = tid & 63;
  int fr = lane & 15, fq = lane >> 4;
  int grow = m0 + arow;
  int t = grow & (T_ - 1);
  const float* xp = x + (long)grow * C_ + acol;
  const bf16* Wp = W + (long)(n0 + wrow) * K + wcol;
  f32x4 a00 = {0.f, 0.f, 0.f, 0.f};
  f32x4 a01 = a00, a02 = a00, a03 = a00, a10 = a00, a11 = a00, a12 = a00, a13 = a00;
  for (int k0 = 0; k0 < K; k0 += 64) {
#pragma unroll
    for (int jj = 0; jj < 4; jj++) {   // 8 cols per jj
      int co = k0 + (jj << 3);
      float4 c0 = *(const float4*)(xp + co);
      float4 c1 = *(const float4*)(xp + co + 4);
      float4 q0 = {0.f, 0.f, 0.f, 0.f}, q1 = q0;
      if (t > 0) {
        q0 = *(const float4*)(xp + co - C_);
        q1 = *(const float4*)(xp + co + 4 - C_);
      }
      float4 m0v = *(const float4*)(tmx + co + acol);
      float4 m1v = *(const float4*)(tmx + co + acol + 4);
      short8 sv;
      sv[0] = bfbits(fmaf(q0.x - c0.x, m0v.x, c0.x));
      sv[1] = bfbits(fmaf(q0.y - c0.y, m0v.y, c0.y));
      sv[2] = bfbits(fmaf(q0.z - c0.z, m0v.z, c0.z));
      sv[3] = bfbits(fmaf(q0.w - c0.w, m0v.w, c0.w));
      sv[4] = bfbits(fmaf(q1.x - c1.x, m1v.x, c1.x));
      sv[5] = bfbits(fmaf(q1.y - c1.y, m1v.y, c1.y));
      sv[6] = bfbits(fmaf(q1.z - c1.z, m1v.z, c1.z));
      sv[7] = bfbits(fmaf(q1.w - c1.w, m1v.w, c1.w));
      *(short8*)&As[arow][acol + (jj << 3)] = sv;
    }
    *(short8*)&Ws[wrow][wcol] = *(const short8*)(Wp + k0);
    *(short8*)&Ws[wrow][wcol + 8] = *(const short8*)(Wp + k0 + 8);
    __syncthreads();
#pragma unroll
    for (int kk = 0; kk < 2; kk++) {
      int ko = (fq << 3) + (kk << 5);
      short8 af0 = *(const short8*)&As[(wv << 5) + fr][ko];
      short8 af1 = *(const short8*)&As[(wv << 5) + 16 + fr][ko];
      short8 b0 = *(const short8*)&Ws[fr][ko];
      short8 b1 = *(const short8*)&Ws[16 + fr][ko];
      short8 b2 = *(const short8*)&Ws[32 + fr][ko];
      short8 b3 = *(const short8*)&Ws[48 + fr][ko];
      a00 = __builtin_amdgcn_mfma_f32_16x16x32_bf16(af0, b0, a00, 0, 0, 0);
      a01 = __builtin_amdgcn_mfma_f32_16x16x32_bf16(af0, b1, a01, 0, 0, 0);
      a02 = __builtin_amdgcn_mfma_f32_16x16x32_bf16(af0, b2, a02, 0, 0, 0);
      a03 = __builtin_amdgcn_mfma_f32_16x16x32_bf16(af0, b3, a03, 0, 0, 0);
      a10 = __builtin_amdgcn_mfma_f32_16x16x32_bf16(af1, b0, a10, 0, 0, 0);
      a11 = __builtin_amdgcn_mfma_f32_16x16x32_bf16(af1, b1, a11, 0, 0, 0);
      a12 = __builtin_amdgcn_mfma_f32_16x16x32_bf16(af1, b2, a12, 0, 0, 0);
      a13 = __builtin_amdgcn_mfma_f32_16x16x32_bf16(af1, b3, a13, 0, 0, 0);
    }
    __syncthreads();
  }
  const int Nz = 128;
  int ocol = n0 + fr;
  int orow0 = m0 + (wv << 5) + (fq << 2);
#define WRM(accv, mf, nt) { int col = ocol + ((nt) << 4); \
    _Pragma("unroll") for (int r = 0; r < 4; r++) { \
      long oi = (long)(orow0 + ((mf) << 4) + r) * Nz + col; \
      Cb[oi] = f2bf(tanhf(accv[r])); } }
  WRM(a00, 0, 0) WRM(a01, 0, 1) WRM(a02, 0, 2) WRM(a03, 0, 3)
  WRM(a10, 1, 0) WRM(a11, 1, 1) WRM(a12, 1, 2) WRM(a13, 1, 3)
#undef WRM
}

// ---------------- K3b: apply deltas -> xrg/xwa/xk/xv (bf16 out) -------------
// Replaces mix4: purely memory-bound. deltas[m][f*1024+c] from the MFMA GEMM;
// xx = xprev - x recomputed inline (L2-hot).
__global__ __launch_bounds__(256) void apply_mix_kernel(
    const float* __restrict__ x, const bf16* __restrict__ deltas,
    const float* __restrict__ tmaa,
    bf16* __restrict__ xrg, bf16* __restrict__ xwa,
    bf16* __restrict__ xk, bf16* __restrict__ xv) {
  long i4 = (long)blockIdx.x * 256 + threadIdx.x;  // < 2048*256
  int m = (int)(i4 >> 8);
  int cq = (int)(i4 & 255) << 2;
  int t = m & (T_ - 1);
  long xo = (long)m * C_ + cq;
  float4 xb = *(const float4*)(x + xo);
  float4 xp = {0.f, 0.f, 0.f, 0.f};
  if (t > 0) xp = *(const float4*)(x + xo - C_);
  float4 xxv = {xp.x - xb.x, xp.y - xb.y, xp.z - xb.z, xp.w - xb.w};
  bf16* outs[4] = {xrg, xwa, xk, xv};
#pragma unroll
  for (int f = 0; f < 4; f++) {
    short4v dl = *(const short4v*)(deltas + (long)m * 4096 + (f << 10) + cq);
    float4 ta = *(const float4*)(tmaa + f * C_ + cq);
    short4v sv;
    sv[0] = bfbits(fmaf(xxv.x, ta.x + bs2f(dl[0]), xb.x));
    sv[1] = bfbits(fmaf(xxv.y, ta.y + bs2f(dl[1]), xb.y));
    sv[2] = bfbits(fmaf(xxv.z, ta.z + bs2f(dl[2]), xb.z));
    sv[3] = bfbits(fmaf(xxv.w, ta.w + bs2f(dl[3]), xb.w));
    *(short4v*)(outs[f] + xo) = sv;
  }
}

// ---------------- K5: stage-2 small GEMMs + gates + per-head kk norm --------
__global__ __launch_bounds__(256) void fuse2_kernel(
    const float* __restrict__ kraw, const float* __restrict__ out1,
    const float* __restrict__ out2,
    const bf16* __restrict__ dw2, const bf16* __restrict__ kkw2,
    const bf16* __restrict__ aw2, const bf16* __restrict__ maw2,
    const bf16* __restrict__ mkw2,
    const float* __restrict__ tdec, const float* __restrict__ taa,
    const float* __restrict__ tma, const float* __restrict__ tmk,
    float* __restrict__ ew, float* __restrict__ kfin,
    float* __restrict__ kkn, float* __restrict__ bbo) {
  int m = blockIdx.x, tid = threadIdx.x;
  __shared__ float w1r[64], kk1r[16], a1r[16], ma1r[16], mk1r[16];
  if (tid < 64) w1r[tid] = out2[(long)m * 96 + tid];
  else if (tid < 80) kk1r[tid - 64] = out1[(long)m * 32 + (tid - 64)];
  else if (tid < 96) a1r[tid - 80] = out2[(long)m * 96 + 64 + (tid - 80)];
  else if (tid < 112) ma1r[tid - 96] = out2[(long)m * 96 + 80 + (tid - 96)];
  else if (tid < 128) mk1r[tid - 112] = out1[(long)m * 32 + 16 + (tid - 112)];
  __syncthreads();
  float kkp[4], av[4], wv[4], kr[4], mkv[4];
  float sumsq = 0.f;
#pragma unroll
  for (int j = 0; j < 4; j++) {
    int c = (tid << 2) + j;
    long off = (long)m * C_ + c;
    float wd = 0.f;
    const short8* dp = (const short8*)(dw2 + ((long)c << 6));
#pragma unroll
    for (int d8 = 0; d8 < 8; d8++) {
      short8 u = dp[d8];
      int db = d8 << 3;
#pragma unroll
      for (int e = 0; e < 8; e++) wd += w1r[db + e] * bs2f(u[e]);
    }
    float w = -softplusf_(-(tdec[c] + wd)) - 0.5f;
    wv[j] = w;
    float kd = 0.f, ad = 0.f, mad = 0.f, mkd = 0.f;
    const short8* kp = (const short8*)(kkw2 + ((long)c << 4));
    const short8* ap = (const short8*)(aw2 + ((long)c << 4));
    const short8* mp = (const short8*)(maw2 + ((long)c << 4));
    const short8* qp = (const short8*)(mkw2 + ((long)c << 4));
#pragma unroll
    for (int d8 = 0; d8 < 2; d8++) {
      short8 u1 = kp[d8], u2 = ap[d8], u3 = mp[d8], u4 = qp[d8];
      int db = d8 << 3;
#pragma unroll
      for (int e = 0; e < 8; e++) {
        kd += kk1r[db + e] * bs2f(u1[e]);
        ad += a1r[db + e] * bs2f(u2[e]);
        mad += ma1r[db + e] * bs2f(u3[e]);
        mkd += mk1r[db + e] * bs2f(u4[e]);
      }
    }
    float krw = kraw[off];
    float kkpre = krw + kd;
    kkp[j] = kkpre;
    sumsq += kkpre * kkpre;
    float a = sigmoidf_(taa[c] + ad);
    av[j] = a;
    float ma = sigmoidf_(tma[c] + mad);
    float mk = sigmoidf_(tmk[c] + mkd);
    mkv[j] = mk;
    kr[j] = krw * (ma + a * (1.f - ma));
  }
  sumsq += __shfl_xor(sumsq, 1);
  sumsq += __shfl_xor(sumsq, 2);
  sumsq += __shfl_xor(sumsq, 4);
  sumsq += __shfl_xor(sumsq, 8);
  float rn = 1.0f / fmaxf(sqrtf(sumsq), 1e-12f);
#pragma unroll
  for (int j = 0; j < 4; j++) {
    int c = (tid << 2) + j;
    long off = (long)m * C_ + c;
    float kknv = kkp[j] * rn;
    kkn[off] = kknv;
    bbo[off] = -kknv * av[j];
    ew[off] = expf(wv[j]);
    kfin[off] = kr[j] * expf(wv[j] * mkv[j]);
  }
}

// ---------------- K6: RWKV-7 scan, 128 blocks x 256 threads -----------------
// R3 structure (dbuf LDS, 3-set rotating register pipeline, sched_barrier) +
// R7 y-pipeline (qsum16x2 overlaps token t's sab chain with t-1's y chain).
// ~300 cyc/token floor: wave-serial ds_read pipeline + DPP latency at 1
// wave/SIMD; resisted packing (R4), scheduling (R3), chain interleave (R7).
#define SCHUNK 16
#define NCHUNK (T_ / SCHUNK)
__global__ __launch_bounds__(256, 1) void scan_kernel(
    const float* __restrict__ rB, const float* __restrict__ ewB,
    const float* __restrict__ kB, const float* __restrict__ vB,
    const float* __restrict__ kkB, const float* __restrict__ bbB,
    float* __restrict__ yB) {
  __shared__ __align__(16) float lds[2][6][SCHUNK * 64];
  int bid = blockIdx.x;          // 0..127
  int bh = bid >> 2, rg = bid & 3;
  int b = bh >> 4, h = bh & 15;
  int tid = threadIdx.x;
  int wave = tid >> 6, lane = tid & 63;
  int g = lane >> 4, q = lane & 15;
  int row = (rg << 4) + (wave << 2) + g;   // this lane's single row
  int kq = q << 2;                         // 4 keys: kq..kq+3
  const long base = ((long)b * T_) * C_ + (h << 6);
  const float* s0 = kkB + base;
  const float* s1 = ewB + base;
  const float* s2 = kB + base;
  const float* s3 = bbB + base;
  const float* s4 = rB + base;
  const float* s5 = vB + base;
  int stok = tid >> 4;           // staging token within chunk (0..15)
  int spc = (tid & 15) << 2;     // float offset within token row
  int lo = (stok << 6) + spc;    // LDS float offset
  float4 rb0, rb1, rb2, rb3, rb4, rb5;
  auto loadc = [&](int c) {
    long go = (long)((c << 4) + stok) * C_ + spc;
    rb0 = *(const float4*)(s0 + go);
    rb1 = *(const float4*)(s1 + go);
    rb2 = *(const float4*)(s2 + go);
    rb3 = *(const float4*)(s3 + go);
    rb4 = *(const float4*)(s4 + go);
    rb5 = *(const float4*)(s5 + go);
  };
  auto stage = [&](int buf) {
    *(float4*)&lds[buf][0][lo] = rb0;
    *(float4*)&lds[buf][1][lo] = rb1;
    *(float4*)&lds[buf][2][lo] = rb2;
    *(float4*)&lds[buf][3][lo] = rb3;
    *(float4*)&lds[buf][4][lo] = rb4;
    *(float4*)&lds[buf][5][lo] = rb5;
  };
  float S0 = 0.f, S1 = 0.f, S2 = 0.f, S3 = 0.f;
  float ypv = 0.f;               // pending y-partial of previous token
  float4 Q0kk, Q0ew, Q0k, Q0bb, Q0r; float Q0v;
  float4 Q1kk, Q1ew, Q1k, Q1bb, Q1r; float Q1v;
  float4 Q2kk, Q2ew, Q2k, Q2bb, Q2r; float Q2v;

#define PF(i, tt) { int tb_ = ((tt) << 6); \
    Q##i##kk = *(const float4*)&lds[cur][0][tb_ + kq]; \
    Q##i##ew = *(const float4*)&lds[cur][1][tb_ + kq]; \
    Q##i##k  = *(const float4*)&lds[cur][2][tb_ + kq]; \
    Q##i##bb = *(const float4*)&lds[cur][3][tb_ + kq]; \
    Q##i##r  = *(const float4*)&lds[cur][4][tb_ + kq]; \
    Q##i##v  = lds[cur][5][tb_ + row]; }
#define SBAR __builtin_amdgcn_sched_barrier(0x7)
#define ST(i, gtok, FIRSTT) { \
    float p_ = fmaf(S1, Q##i##kk.y, S0 * Q##i##kk.x) + \
               fmaf(S3, Q##i##kk.w, S2 * Q##i##kk.z); \
    float yo_ = ypv; \
    qsum16x2(p_, yo_); \
    if (q == 0 && !((FIRSTT) && c == 0)) \
      yB[base + (long)((gtok) - 1) * C_ + row] = yo_; \
    float n0 = fmaf(S0, Q##i##ew.x, Q##i##v * Q##i##k.x); \
    float n1 = fmaf(S1, Q##i##ew.y, Q##i##v * Q##i##k.y); \
    float n2 = fmaf(S2, Q##i##ew.z, Q##i##v * Q##i##k.z); \
    float n3 = fmaf(S3, Q##i##ew.w, Q##i##v * Q##i##k.w); \
    S0 = fmaf(p_, Q##i##bb.x, n0); \
    S1 = fmaf(p_, Q##i##bb.y, n1); \
    S2 = fmaf(p_, Q##i##bb.z, n2); \
    S3 = fmaf(p_, Q##i##bb.w, n3); \
    ypv = fmaf(S1, Q##i##r.y, S0 * Q##i##r.x) + \
          fmaf(S3, Q##i##r.w, S2 * Q##i##r.z); }

  loadc(0);
  stage(0);
  loadc(1);
  __syncthreads();
  int cur = 0;
  for (int c = 0; c < NCHUNK; c++) {
    int t0 = c << 4;
    PF(0, 0); PF(1, 1);
    if (c + 1 < NCHUNK) stage(cur ^ 1);
    if (c + 2 < NCHUNK) loadc(c + 2);
    SBAR;
    PF(2, 2);  SBAR; ST(0, t0 + 0, true);
    PF(0, 3);  SBAR; ST(1, t0 + 1, false);
    PF(1, 4);  SBAR; ST(2, t0 + 2, false);
    PF(2, 5);  SBAR; ST(0, t0 + 3, false);
    PF(0, 6);  SBAR; ST(1, t0 + 4, false);
    PF(1, 7);  SBAR; ST(2, t0 + 5, false);
    PF(2, 8);  SBAR; ST(0, t0 + 6, false);
    PF(0, 9);  SBAR; ST(1, t0 + 7, false);
    PF(1, 10); SBAR; ST(2, t0 + 8, false);
    PF(2, 11); SBAR; ST(0, t0 + 9, false);
    PF(0, 12); SBAR; ST(1, t0 + 10, false);
    PF(1, 13); SBAR; ST(2, t0 + 11, false);
    PF(2, 14); SBAR; ST(0, t0 + 12, false);
    PF(0, 15); SBAR; ST(1, t0 + 13, false);
    ST(2, t0 + 14, false);
    ST(0, t0 + 15, false);
    __syncthreads();
    cur ^= 1;
  }
  {
    float yo = qsum16(ypv);
    if (q == 0) yB[base + (long)(T_ - 1) * C_ + row] = yo;
  }
#undef PF
#undef SBAR
#undef ST
}

// ---------------- K7: GroupNorm + bonus + gate (bf16 out) -------------------
__global__ __launch_bounds__(256) void gnout_kernel(
    const float* __restrict__ y, const float* __restrict__ r,
    const float* __restrict__ kf, const float* __restrict__ v,
    const float* __restrict__ g,
    const float* __restrict__ lnw, const float* __restrict__ lnb,
    const float* __restrict__ fa, bf16* __restrict__ z) {
  int tid = threadIdx.x;
  int w = tid >> 6, lane = tid & 63;
  int gi = (blockIdx.x << 2) + w;  // (b*T+t)*H + h
  int h = gi & 15, mt = gi >> 4;
  long off = (long)mt * C_ + (h << 6) + lane;
  float yv = y[off];
  float s = yv;
  s += __shfl_xor(s, 1); s += __shfl_xor(s, 2); s += __shfl_xor(s, 4);
  s += __shfl_xor(s, 8); s += __shfl_xor(s, 16); s += __shfl_xor(s, 32);
  float mu = s * (1.0f / 64.0f);
  float d = yv - mu;
  float s2 = d * d;
  s2 += __shfl_xor(s2, 1); s2 += __shfl_xor(s2, 2); s2 += __shfl_xor(s2, 4);
  s2 += __shfl_xor(s2, 8); s2 += __shfl_xor(s2, 16); s2 += __shfl_xor(s2, 32);
  float var = s2 * (1.0f / 64.0f);
  int hc = (h << 6) + lane;
  float dot = r[off] * kf[off] * fa[hc];
  dot += __shfl_xor(dot, 1); dot += __shfl_xor(dot, 2); dot += __shfl_xor(dot, 4);
  dot += __shfl_xor(dot, 8); dot += __shfl_xor(dot, 16); dot += __shfl_xor(dot, 32);
  float yn = d * rsqrtf(var + 0.00064f) * lnw[hc] + lnb[hc];
  z[off] = f2bf((yn + dot * v[off]) * g[off]);
}

extern "C" void kernel_launch(void* const* d_in, const int* in_sizes, int n_in,
                              void* d_out, int out_size, void* d_ws, size_t ws_size,
                              hipStream_t stream) {
  const float* x = (const float*)d_in[0];
  const float* tmx = (const float*)d_in[1];
  const float* tmaa = (const float*)d_in[2];
  const float* tmw1 = (const float*)d_in[3];
  const float* tmw2 = (const float*)d_in[4];
  const float* tdec = (const float*)d_in[5];
  const float* tdw1 = (const float*)d_in[6];
  const float* tdw2 = (const float*)d_in[7];
  const float* taa5 = (const float*)d_in[8];
  const float* taw1 = (const float*)d_in[9];
  const float* taw2 = (const float*)d_in[10];
  const float* tkw1 = (const float*)d_in[11];
  const float* tkw2 = (const float*)d_in[12];
  const float* gw1 = (const float*)d_in[13];
  const float* gw2 = (const float*)d_in[14];
  const float* tmia = (const float*)d_in[15];
  const float* maw1 = (const float*)d_in[16];
  const float* maw2 = (const float*)d_in[17];
  const float* tmik = (const float*)d_in[18];
  const float* mkw1 = (const float*)d_in[19];
  const float* mkw2 = (const float*)d_in[20];
  const float* wrec = (const float*)d_in[21];
  const float* wkey = (const float*)d_in[22];
  const float* wval = (const float*)d_in[23];
  const float* wout = (const float*)d_in[24];
  const float* lnw = (const float*)d_in[25];
  const float* lnb = (const float*)d_in[26];
  const float* faaa = (const float*)d_in[27];

  const long MT = 2048, CC = 1024;
  char* base = (char*)d_ws;
  float* xx = (float*)base;    base += MT * CC * 4;   // y lives here
  bf16* xxxb = (bf16*)base;    base += MT * CC * 2;   // unused (layout keep)
  bf16* xrgb = (bf16*)base;    base += MT * CC * 2;   // ┐ kfin overlays (8MB)
  bf16* xwab = (bf16*)base;    base += MT * CC * 2;   // ┘
  bf16* xkb = (bf16*)base;     base += MT * CC * 2;   // ┐ kkn overlays (8MB)
  bf16* xvb = (bf16*)base;     base += MT * CC * 2;   // ┘
  float* rr = (float*)base;    base += MT * CC * 4;
  float* kraw = (float*)base;  base += MT * CC * 4;   // also ew
  float* vv = (float*)base;    base += MT * CC * 4;
  float* gg = (float*)base;    base += MT * CC * 4;
  float* bbo = (float*)base;   base += MT * CC * 4;
  float* mix = (float*)base;   base += MT * 128 * 4;  // unused (layout keep)
  bf16* g1b = (bf16*)base;     base += MT * 128 * 2;
  float* out1 = (float*)base;  base += MT * 32 * 4;   // [kk1|mk1]
  float* out2 = (float*)base;  base += MT * 96 * 4;   // [w1|a1|ma1]
  bf16* zb = (bf16*)base;      base += MT * CC * 2;
  bf16* tmw1b = (bf16*)base;   base += 128 * CC * 2;
  bf16* wrecb = (bf16*)base;   base += CC * CC * 2;
  bf16* gw1b = (bf16*)base;    base += 128 * CC * 2;
  bf16* gw2b = (bf16*)base;    base += CC * 128 * 2;
  bf16* wkeyb = (bf16*)base;   base += CC * CC * 2;
  bf16* wvalb = (bf16*)base;   base += CC * CC * 2;
  bf16* woutb = (bf16*)base;   base += CC * CC * 2;
  bf16* wskb = (bf16*)base;    base += 32 * CC * 2;
  bf16* wswab = (bf16*)base;   base += 96 * CC * 2;
  bf16* tmw2b = (bf16*)base;   base += 4 * CC * 32 * 2;  // unused (layout keep)
  bf16* tdw2b = (bf16*)base;   base += CC * 64 * 2;
  bf16* tkw2b = (bf16*)base;   base += CC * 16 * 2;
  bf16* taw2b = (bf16*)base;   base += CC * 16 * 2;
  bf16* maw2b = (bf16*)base;   base += CC * 16 * 2;
  bf16* mkw2b = (bf16*)base;   base += CC * 16 * 2;
  // R8 additions:
  bf16* mixb = (bf16*)base;    base += MT * 128 * 2;     // bf16 mix (GEMM A)
  bf16* tmw2e = (bf16*)base;   base += 4096L * 128 * 2;  // expanded W''
  bf16* deltasb = (bf16*)base; base += MT * 4096L * 2;   // deltas (2048x4096)
  // aliases (dead-buffer reuse, verified non-overlapping in time):
  float* ew = kraw;            // fuse2 reads kraw then writes ew at same offs
  float* kfin = (float*)xrgb;  // xrg/xwa bf16 dead before fuse2
  float* kkn = (float*)xkb;    // xk/xv bf16 dead before fuse2
  float* y = xx;               // xx region reused for y
  (void)xxxb; (void)mix; (void)tmw2b;

  cvt_all_kernel<<<5248, 256, 0, stream>>>(
      tmw1, wrec, gw1, gw2, wkey, wval, wout,
      tmw1b, wrecb, gw1b, gw2b, wkeyb, wvalb, woutb,
      tkw1, mkw1, tdw1, taw1, maw1, wskb, wswab,
      tmw2, tdw2, tkw2, taw2, maw2, mkw2,
      tmw2e, tdw2b, tkw2b, taw2b, maw2b, mkw2b);

  // mix GEMM with fused token-shift A-staging (bf16 out)
  gemm_mix_kernel<<<dim3(2, 16), 256, 0, stream>>>(x, tmx, tmw1b, mixb);
  // deltas GEMM: (2048x128) x (4096x128)^T -> bf16 deltas
  {
    GemmBatch gb = {};
    gb.A[0] = mixb; gb.W[0] = tmw2e; gb.Cf[0] = nullptr; gb.Cb[0] = deltasb;
    gb.N[0] = 4096; gb.actN[0] = 0;
    gemm_batch_kernel<<<dim3(64, 16, 1), 256, 0, stream>>>(gb, 128);
  }
  apply_mix_kernel<<<2048, 256, 0, stream>>>(x, deltasb, tmaa,
                                             xrgb, xwab, xkb, xvb);
  // 6 independent K=1024 GEMMs, one launch
  {
    GemmBatch gb = {};
    gb.A[0] = xrgb; gb.W[0] = wrecb; gb.Cf[0] = rr;   gb.Cb[0] = nullptr; gb.N[0] = 1024; gb.actN[0] = 0;
    gb.A[1] = xrgb; gb.W[1] = gw1b;  gb.Cf[1] = nullptr; gb.Cb[1] = g1b;  gb.N[1] = 128;  gb.actN[1] = 128;
    gb.A[2] = xkb;  gb.W[2] = wkeyb; gb.Cf[2] = kraw; gb.Cb[2] = nullptr; gb.N[2] = 1024; gb.actN[2] = 0;
    gb.A[3] = xkb;  gb.W[3] = wskb;  gb.Cf[3] = out1; gb.Cb[3] = nullptr; gb.N[3] = 32;   gb.actN[3] = 16;
    gb.A[4] = xvb;  gb.W[4] = wvalb; gb.Cf[4] = vv;   gb.Cb[4] = nullptr; gb.N[4] = 1024; gb.actN[4] = 0;
    gb.A[5] = xwab; gb.W[5] = wswab; gb.Cf[5] = out2; gb.Cb[5] = nullptr; gb.N[5] = 96;   gb.actN[5] = 64;
    gemm_batch_kernel<<<dim3(16, 16, 6), 256, 0, stream>>>(gb, 1024);
  }
  // gg GEMM: (2048x128)x(1024x128)^T
  {
    GemmBatch gb = {};
    gb.A[0] = g1b; gb.W[0] = gw2b; gb.Cf[0] = gg; gb.Cb[0] = nullptr;
    gb.N[0] = 1024; gb.actN[0] = 0;
    gemm_batch_kernel<<<dim3(16, 16, 1), 256, 0, stream>>>(gb, 128);
  }
  fuse2_kernel<<<2048, 256, 0, stream>>>(kraw, out1, out2,
                                         tdw2b, tkw2b, taw2b, maw2b, mkw2b,
                                         tdec, taa5, tmia, tmik,
                                         ew, kfin, kkn, bbo);
  scan_kernel<<<128, 256, 0, stream>>>(rr, ew, kfin, vv, kkn, bbo, y);
  gnout_kernel<<<8192, 256, 0, stream>>>(y, rr, kfin, vv, gg, lnw, lnb, faaa, zb);
  // output GEMM: (2048x1024)x(1024x1024)^T
  {
    GemmBatch gb = {};
    gb.A[0] = zb; gb.W[0] = woutb; gb.Cf[0] = (float*)d_out; gb.Cb[0] = nullptr;
    gb.N[0] = 1024; gb.actN[0] = 0;
    gemm_batch_kernel<<<dim3(16, 16, 1), 256, 0, stream>>>(gb, 1024);
  }
}

// Round 9
// 429.550 us; speedup vs baseline: 1.5220x; 1.2168x over previous
//
#include <hip/hip_runtime.h>
#include <hip/hip_bf16.h>

typedef __hip_bfloat16 bf16;

#define B_ 2
#define T_ 1024
#define C_ 1024
#define H_ 16
#define N_ 64

using short4v = __attribute__((ext_vector_type(4))) short;
using short8 = __attribute__((ext_vector_type(8))) short;
using f32x4 = __attribute__((ext_vector_type(4))) float;

__device__ __forceinline__ float bs2f(short s) {
  return __uint_as_float(((unsigned int)(unsigned short)s) << 16);
}
__device__ __forceinline__ bf16 f2bf(float f) { return __float2bfloat16(f); }
__device__ __forceinline__ short bfbits(float f) {
  bf16 h = __float2bfloat16(f);
  return *reinterpret_cast<short*>(&h);
}
__device__ __forceinline__ float sigmoidf_(float x) { return 1.0f / (1.0f + expf(-x)); }
__device__ __forceinline__ float softplusf_(float x) {
  return fmaxf(x, 0.0f) + log1pf(expf(-fabsf(x)));
}
// Full 16-lane-row sum, all lanes receive the result. Pure-VALU DPP.
__device__ __forceinline__ float qsum16(float x) {
  int a = __builtin_amdgcn_update_dpp(0, __float_as_int(x), 0xB1, 0xF, 0xF, true);
  x += __int_as_float(a);
  int b = __builtin_amdgcn_update_dpp(0, __float_as_int(x), 0x4E, 0xF, 0xF, true);
  x += __int_as_float(b);
  int c = __builtin_amdgcn_update_dpp(0, __float_as_int(x), 0x124, 0xF, 0xF, true);
  x += __int_as_float(c);
  int d = __builtin_amdgcn_update_dpp(0, __float_as_int(x), 0x128, 0xF, 0xF, true);
  x += __int_as_float(d);
  return x;
}
// Two interleaved 16-lane-row sums (overlaps token t's sab chain with token
// t-1's y chain; see scan_kernel comment).
__device__ __forceinline__ void qsum16x2(float& x, float& y) {
  int a0 = __builtin_amdgcn_update_dpp(0, __float_as_int(x), 0xB1, 0xF, 0xF, true);
  int b0 = __builtin_amdgcn_update_dpp(0, __float_as_int(y), 0xB1, 0xF, 0xF, true);
  x += __int_as_float(a0); y += __int_as_float(b0);
  int a1 = __builtin_amdgcn_update_dpp(0, __float_as_int(x), 0x4E, 0xF, 0xF, true);
  int b1 = __builtin_amdgcn_update_dpp(0, __float_as_int(y), 0x4E, 0xF, 0xF, true);
  x += __int_as_float(a1); y += __int_as_float(b1);
  int a2 = __builtin_amdgcn_update_dpp(0, __float_as_int(x), 0x124, 0xF, 0xF, true);
  int b2 = __builtin_amdgcn_update_dpp(0, __float_as_int(y), 0x124, 0xF, 0xF, true);
  x += __int_as_float(a2); y += __int_as_float(b2);
  int a3 = __builtin_amdgcn_update_dpp(0, __float_as_int(x), 0x128, 0xF, 0xF, true);
  int b3 = __builtin_amdgcn_update_dpp(0, __float_as_int(y), 0x128, 0xF, 0xF, true);
  x += __int_as_float(a3); y += __int_as_float(b3);
}

// ---------------- K0: ALL weight conversions + expansions, one launch -------
// tmw2e (4096x128): block-diag expansion of tmw2 -> mix-deltas GEMM.
// w2e5 (5120x128): block-diag expansion of {tdw2,taw2,maw2,tkw2,mkw2} -> the
// fuse2 LoRA-2 dots become ONE GEMM (kills fuse2's 512MB L2 weight storm).
// A-col layout for w2e5: [w1(0:64)|a1(64:80)|ma1(80:96)|kk1(96:112)|mk1(112:128)]
__global__ __launch_bounds__(256) void cvt_all_kernel(
    const float* __restrict__ s0, const float* __restrict__ s1,
    const float* __restrict__ s2, const float* __restrict__ s3,
    const float* __restrict__ s4, const float* __restrict__ s5,
    const float* __restrict__ s6,
    bf16* __restrict__ d0, bf16* __restrict__ d1, bf16* __restrict__ d2w,
    bf16* __restrict__ d3, bf16* __restrict__ d4, bf16* __restrict__ d5,
    bf16* __restrict__ d6,
    const float* __restrict__ tkw1, const float* __restrict__ mkw1,
    const float* __restrict__ tdw1, const float* __restrict__ taw1,
    const float* __restrict__ maw1,
    bf16* __restrict__ wsk, bf16* __restrict__ wswa,
    const float* __restrict__ tmw2, const float* __restrict__ tdw2,
    const float* __restrict__ tkw2, const float* __restrict__ taw2,
    const float* __restrict__ maw2, const float* __restrict__ mkw2,
    bf16* __restrict__ tmw2e, bf16* __restrict__ w2e5) {
  long bidx = blockIdx.x;
  const float* s; bf16* d; long off;
  if (bidx < 4480) {                      // big weights
    long i4 = bidx * 256 + threadIdx.x;
    if (i4 < 32768) { s = s0; d = d0; off = i4; }
    else if (i4 < 294912) { s = s1; d = d1; off = i4 - 32768; }
    else if (i4 < 327680) { s = s2; d = d2w; off = i4 - 294912; }
    else if (i4 < 360448) { s = s3; d = d3; off = i4 - 327680; }
    else if (i4 < 622592) { s = s4; d = d4; off = i4 - 360448; }
    else if (i4 < 884736) { s = s5; d = d5; off = i4 - 622592; }
    else { s = s6; d = d6; off = i4 - 884736; }
  } else if (bidx < 4608) {               // LoRA-1 packs
    long i4 = (bidx - 4480) * 256 + threadIdx.x;  // < 32768
    long so, dof;
    if (i4 < 4096) { s = tkw1; so = i4; d = wsk; dof = i4; }
    else if (i4 < 8192) { s = mkw1; so = i4 - 4096; d = wsk; dof = i4; }
    else if (i4 < 24576) { s = tdw1; so = i4 - 8192; d = wswa; dof = i4 - 8192; }
    else if (i4 < 28672) { s = taw1; so = i4 - 24576; d = wswa; dof = i4 - 8192; }
    else { s = maw1; so = i4 - 28672; d = wswa; dof = i4 - 8192; }
    float4 v = *(const float4*)(s + so * 4);
    d[dof * 4 + 0] = f2bf(v.x); d[dof * 4 + 1] = f2bf(v.y);
    d[dof * 4 + 2] = f2bf(v.z); d[dof * 4 + 3] = f2bf(v.w);
    return;
  } else if (bidx < 5120) {               // tmw2e expansion (4096x128)
    long i4 = (bidx - 4608) * 256 + threadIdx.x;  // < 131072
    long n = i4 >> 5;
    int k0 = (int)(i4 & 31) << 2;
    int f = (int)(n >> 10);
    float4 v = {0.f, 0.f, 0.f, 0.f};
    if ((k0 >> 5) == f) v = *(const float4*)(tmw2 + n * 32 + (k0 & 31));
    tmw2e[i4 * 4 + 0] = f2bf(v.x);
    tmw2e[i4 * 4 + 1] = f2bf(v.y);
    tmw2e[i4 * 4 + 2] = f2bf(v.z);
    tmw2e[i4 * 4 + 3] = f2bf(v.w);
    return;
  } else {                                // w2e5 expansion (5120x128)
    long i4 = (bidx - 5120) * 256 + threadIdx.x;  // < 163840
    long rowi = i4 >> 5;                  // 0..5119
    int k0 = (int)(i4 & 31) << 2;         // 0..124
    int j = (int)(rowi >> 10);
    int c = (int)(rowi & 1023);
    float4 v = {0.f, 0.f, 0.f, 0.f};
    if (j == 0) { if (k0 < 64) v = *(const float4*)(tdw2 + c * 64 + k0); }
    else if (j == 1) { if (k0 >= 64 && k0 < 80) v = *(const float4*)(taw2 + c * 16 + (k0 - 64)); }
    else if (j == 2) { if (k0 >= 80 && k0 < 96) v = *(const float4*)(maw2 + c * 16 + (k0 - 80)); }
    else if (j == 3) { if (k0 >= 96 && k0 < 112) v = *(const float4*)(tkw2 + c * 16 + (k0 - 96)); }
    else { if (k0 >= 112) v = *(const float4*)(mkw2 + c * 16 + (k0 - 112)); }
    w2e5[i4 * 4 + 0] = f2bf(v.x);
    w2e5[i4 * 4 + 1] = f2bf(v.y);
    w2e5[i4 * 4 + 2] = f2bf(v.z);
    w2e5[i4 * 4 + 3] = f2bf(v.w);
    return;
  }
  float4 v = *(const float4*)(s + off * 4);
  d[off * 4 + 0] = f2bf(v.x);
  d[off * 4 + 1] = f2bf(v.y);
  d[off * 4 + 2] = f2bf(v.z);
  d[off * 4 + 3] = f2bf(v.w);
}

// ---------------- Batched MFMA GEMM: C[z] = A[z] * W[z]^T -------------------
// 128x64 tile, 4 waves x (2 M-frags x 4 N-frags). ldc/coff let several GEMMs
// write column slices of one combined buffer (out12).
struct GemmBatch {
  const bf16* A[6]; const bf16* W[6];
  float* Cf[6]; bf16* Cb[6];
  int N[6]; int actN[6]; int ldc[6]; int coff[6];
};

__global__ __launch_bounds__(256) void gemm_batch_kernel(GemmBatch gb, int K) {
  __shared__ __align__(16) bf16 As[128][72];
  __shared__ __align__(16) bf16 Ws[64][72];
  int z = blockIdx.z;
  int Nz = gb.N[z];
  int n0 = blockIdx.x << 6;
  if (n0 >= Nz) return;
  int m0 = blockIdx.y << 7;
  int actN = gb.actN[z];
  int ldc = gb.ldc[z], coff = gb.coff[z];
  const bf16* A = gb.A[z];
  const bf16* W = gb.W[z];
  float* Cf = gb.Cf[z];
  bf16* Cb = gb.Cb[z];
  int tid = threadIdx.x;
  int arow = tid >> 1, acol = (tid & 1) << 5;
  int wrow = tid >> 2, wcol = (tid & 3) << 4;
  int wv = tid >> 6, lane = tid & 63;
  int fr = lane & 15, fq = lane >> 4;
  bool wok = (n0 + wrow) < Nz;
  const bf16* Ap = A + (long)(m0 + arow) * K + acol;
  const bf16* Wp = W + (long)(n0 + wrow) * K + wcol;
  short8 zz = {0, 0, 0, 0, 0, 0, 0, 0};
  f32x4 a00 = {0.f, 0.f, 0.f, 0.f};
  f32x4 a01 = a00, a02 = a00, a03 = a00, a10 = a00, a11 = a00, a12 = a00, a13 = a00;
  for (int k0 = 0; k0 < K; k0 += 64) {
    *(short8*)&As[arow][acol] = *(const short8*)(Ap + k0);
    *(short8*)&As[arow][acol + 8] = *(const short8*)(Ap + k0 + 8);
    *(short8*)&As[arow][acol + 16] = *(const short8*)(Ap + k0 + 16);
    *(short8*)&As[arow][acol + 24] = *(const short8*)(Ap + k0 + 24);
    *(short8*)&Ws[wrow][wcol] = wok ? *(const short8*)(Wp + k0) : zz;
    *(short8*)&Ws[wrow][wcol + 8] = wok ? *(const short8*)(Wp + k0 + 8) : zz;
    __syncthreads();
#pragma unroll
    for (int kk = 0; kk < 2; kk++) {
      int ko = (fq << 3) + (kk << 5);
      short8 af0 = *(const short8*)&As[(wv << 5) + fr][ko];
      short8 af1 = *(const short8*)&As[(wv << 5) + 16 + fr][ko];
      short8 b0 = *(const short8*)&Ws[fr][ko];
      short8 b1 = *(const short8*)&Ws[16 + fr][ko];
      short8 b2 = *(const short8*)&Ws[32 + fr][ko];
      short8 b3 = *(const short8*)&Ws[48 + fr][ko];
      a00 = __builtin_amdgcn_mfma_f32_16x16x32_bf16(af0, b0, a00, 0, 0, 0);
      a01 = __builtin_amdgcn_mfma_f32_16x16x32_bf16(af0, b1, a01, 0, 0, 0);
      a02 = __builtin_amdgcn_mfma_f32_16x16x32_bf16(af0, b2, a02, 0, 0, 0);
      a03 = __builtin_amdgcn_mfma_f32_16x16x32_bf16(af0, b3, a03, 0, 0, 0);
      a10 = __builtin_amdgcn_mfma_f32_16x16x32_bf16(af1, b0, a10, 0, 0, 0);
      a11 = __builtin_amdgcn_mfma_f32_16x16x32_bf16(af1, b1, a11, 0, 0, 0);
      a12 = __builtin_amdgcn_mfma_f32_16x16x32_bf16(af1, b2, a12, 0, 0, 0);
      a13 = __builtin_amdgcn_mfma_f32_16x16x32_bf16(af1, b3, a13, 0, 0, 0);
    }
    __syncthreads();
  }
  int ocol = n0 + fr;
  int orow0 = m0 + (wv << 5) + (fq << 2);
#define WRB(accv, mf, nt) { int col = ocol + ((nt) << 4); if (col < Nz) { \
    _Pragma("unroll") for (int r = 0; r < 4; r++) { \
      float vvv = accv[r]; if (col < actN) vvv = tanhf(vvv); \
      long oi = (long)(orow0 + ((mf) << 4) + r) * ldc + coff + col; \
      if (Cb) Cb[oi] = f2bf(vvv); else Cf[oi] = vvv; } } }
  WRB(a00, 0, 0) WRB(a01, 0, 1) WRB(a02, 0, 2) WRB(a03, 0, 3)
  WRB(a10, 1, 0) WRB(a11, 1, 1) WRB(a12, 1, 2) WRB(a13, 1, 3)
#undef WRB
}

// ---------------- mix GEMM with fused token-shift A-staging -----------------
// A = xxx = x + (xprev - x)*tmx computed on the fly from f32 x. N=128,
// K=1024, tanh all, bf16 out (feeds the deltas GEMM).
__global__ __launch_bounds__(256) void gemm_mix_kernel(
    const float* __restrict__ x, const float* __restrict__ tmx,
    const bf16* __restrict__ W, bf16* __restrict__ Cb) {
  __shared__ __align__(16) bf16 As[128][72];
  __shared__ __align__(16) bf16 Ws[64][72];
  const int K = 1024;
  int n0 = blockIdx.x << 6;
  int m0 = blockIdx.y << 7;
  int tid = threadIdx.x;
  int arow = tid >> 1, acol = (tid & 1) << 5;
  int wrow = tid >> 2, wcol = (tid & 3) << 4;
  int wv = tid >> 6, lane = tid & 63;
  int fr = lane & 15, fq = lane >> 4;
  int grow = m0 + arow;
  int t = grow & (T_ - 1);
  const float* xp = x + (long)grow * C_ + acol;
  const bf16* Wp = W + (long)(n0 + wrow) * K + wcol;
  f32x4 a00 = {0.f, 0.f, 0.f, 0.f};
  f32x4 a01 = a00, a02 = a00, a03 = a00, a10 = a00, a11 = a00, a12 = a00, a13 = a00;
  for (int k0 = 0; k0 < K; k0 += 64) {
#pragma unroll
    for (int jj = 0; jj < 4; jj++) {
      int co = k0 + (jj << 3);
      float4 c0 = *(const float4*)(xp + co);
      float4 c1 = *(const float4*)(xp + co + 4);
      float4 q0 = {0.f, 0.f, 0.f, 0.f}, q1 = q0;
      if (t > 0) {
        q0 = *(const float4*)(xp + co - C_);
        q1 = *(const float4*)(xp + co + 4 - C_);
      }
      float4 m0v = *(const float4*)(tmx + co + acol);
      float4 m1v = *(const float4*)(tmx + co + acol + 4);
      short8 sv;
      sv[0] = bfbits(fmaf(q0.x - c0.x, m0v.x, c0.x));
      sv[1] = bfbits(fmaf(q0.y - c0.y, m0v.y, c0.y));
      sv[2] = bfbits(fmaf(q0.z - c0.z, m0v.z, c0.z));
      sv[3] = bfbits(fmaf(q0.w - c0.w, m0v.w, c0.w));
      sv[4] = bfbits(fmaf(q1.x - c1.x, m1v.x, c1.x));
      sv[5] = bfbits(fmaf(q1.y - c1.y, m1v.y, c1.y));
      sv[6] = bfbits(fmaf(q1.z - c1.z, m1v.z, c1.z));
      sv[7] = bfbits(fmaf(q1.w - c1.w, m1v.w, c1.w));
      *(short8*)&As[arow][acol + (jj << 3)] = sv;
    }
    *(short8*)&Ws[wrow][wcol] = *(const short8*)(Wp + k0);
    *(short8*)&Ws[wrow][wcol + 8] = *(const short8*)(Wp + k0 + 8);
    __syncthreads();
#pragma unroll
    for (int kk = 0; kk < 2; kk++) {
      int ko = (fq << 3) + (kk << 5);
      short8 af0 = *(const short8*)&As[(wv << 5) + fr][ko];
      short8 af1 = *(const short8*)&As[(wv << 5) + 16 + fr][ko];
      short8 b0 = *(const short8*)&Ws[fr][ko];
      short8 b1 = *(const short8*)&Ws[16 + fr][ko];
      short8 b2 = *(const short8*)&Ws[32 + fr][ko];
      short8 b3 = *(const short8*)&Ws[48 + fr][ko];
      a00 = __builtin_amdgcn_mfma_f32_16x16x32_bf16(af0, b0, a00, 0, 0, 0);
      a01 = __builtin_amdgcn_mfma_f32_16x16x32_bf16(af0, b1, a01, 0, 0, 0);
      a02 = __builtin_amdgcn_mfma_f32_16x16x32_bf16(af0, b2, a02, 0, 0, 0);
      a03 = __builtin_amdgcn_mfma_f32_16x16x32_bf16(af0, b3, a03, 0, 0, 0);
      a10 = __builtin_amdgcn_mfma_f32_16x16x32_bf16(af1, b0, a10, 0, 0, 0);
      a11 = __builtin_amdgcn_mfma_f32_16x16x32_bf16(af1, b1, a11, 0, 0, 0);
      a12 = __builtin_amdgcn_mfma_f32_16x16x32_bf16(af1, b2, a12, 0, 0, 0);
      a13 = __builtin_amdgcn_mfma_f32_16x16x32_bf16(af1, b3, a13, 0, 0, 0);
    }
    __syncthreads();
  }
  const int Nz = 128;
  int ocol = n0 + fr;
  int orow0 = m0 + (wv << 5) + (fq << 2);
#define WRM(accv, mf, nt) { int col = ocol + ((nt) << 4); \
    _Pragma("unroll") for (int r = 0; r < 4; r++) { \
      long oi = (long)(orow0 + ((mf) << 4) + r) * Nz + col; \
      Cb[oi] = f2bf(tanhf(accv[r])); } }
  WRM(a00, 0, 0) WRM(a01, 0, 1) WRM(a02, 0, 2) WRM(a03, 0, 3)
  WRM(a10, 1, 0) WRM(a11, 1, 1) WRM(a12, 1, 2) WRM(a13, 1, 3)
#undef WRM
}

// ---------------- deltas GEMM with fused mix-apply epilogue -----------------
// deltas = mixb(2048x128) x tmw2e(4096x128)^T; each 64-col block belongs to
// exactly one f (= n0>>10), so the epilogue applies
// out_f[m][c] = x + (xprev-x)*(tmaa_f[c] + delta) directly (apply_mix kernel
// and the 16MB deltas roundtrip are gone; delta stays fp32).
__global__ __launch_bounds__(256) void gemm_mixapply_kernel(
    const bf16* __restrict__ A, const bf16* __restrict__ W,
    const float* __restrict__ x, const float* __restrict__ tmaa,
    bf16* __restrict__ xrg, bf16* __restrict__ xwa,
    bf16* __restrict__ xk, bf16* __restrict__ xv) {
  __shared__ __align__(16) bf16 As[128][72];
  __shared__ __align__(16) bf16 Ws[64][72];
  const int K = 128;
  int n0 = blockIdx.x << 6;   // 0..4032
  int m0 = blockIdx.y << 7;
  int tid = threadIdx.x;
  int arow = tid >> 1, acol = (tid & 1) << 5;
  int wrow = tid >> 2, wcol = (tid & 3) << 4;
  int wv = tid >> 6, lane = tid & 63;
  int fr = lane & 15, fq = lane >> 4;
  const bf16* Ap = A + (long)(m0 + arow) * K + acol;
  const bf16* Wp = W + (long)(n0 + wrow) * K + wcol;
  f32x4 a00 = {0.f, 0.f, 0.f, 0.f};
  f32x4 a01 = a00, a02 = a00, a03 = a00, a10 = a00, a11 = a00, a12 = a00, a13 = a00;
  for (int k0 = 0; k0 < K; k0 += 64) {
    *(short8*)&As[arow][acol] = *(const short8*)(Ap + k0);
    *(short8*)&As[arow][acol + 8] = *(const short8*)(Ap + k0 + 8);
    *(short8*)&As[arow][acol + 16] = *(const short8*)(Ap + k0 + 16);
    *(short8*)&As[arow][acol + 24] = *(const short8*)(Ap + k0 + 24);
    *(short8*)&Ws[wrow][wcol] = *(const short8*)(Wp + k0);
    *(short8*)&Ws[wrow][wcol + 8] = *(const short8*)(Wp + k0 + 8);
    __syncthreads();
#pragma unroll
    for (int kk = 0; kk < 2; kk++) {
      int ko = (fq << 3) + (kk << 5);
      short8 af0 = *(const short8*)&As[(wv << 5) + fr][ko];
      short8 af1 = *(const short8*)&As[(wv << 5) + 16 + fr][ko];
      short8 b0 = *(const short8*)&Ws[fr][ko];
      short8 b1 = *(const short8*)&Ws[16 + fr][ko];
      short8 b2 = *(const short8*)&Ws[32 + fr][ko];
      short8 b3 = *(const short8*)&Ws[48 + fr][ko];
      a00 = __builtin_amdgcn_mfma_f32_16x16x32_bf16(af0, b0, a00, 0, 0, 0);
      a01 = __builtin_amdgcn_mfma_f32_16x16x32_bf16(af0, b1, a01, 0, 0, 0);
      a02 = __builtin_amdgcn_mfma_f32_16x16x32_bf16(af0, b2, a02, 0, 0, 0);
      a03 = __builtin_amdgcn_mfma_f32_16x16x32_bf16(af0, b3, a03, 0, 0, 0);
      a10 = __builtin_amdgcn_mfma_f32_16x16x32_bf16(af1, b0, a10, 0, 0, 0);
      a11 = __builtin_amdgcn_mfma_f32_16x16x32_bf16(af1, b1, a11, 0, 0, 0);
      a12 = __builtin_amdgcn_mfma_f32_16x16x32_bf16(af1, b2, a12, 0, 0, 0);
      a13 = __builtin_amdgcn_mfma_f32_16x16x32_bf16(af1, b3, a13, 0, 0, 0);
    }
    __syncthreads();
  }
  int f = n0 >> 10;
  int c0 = n0 & 1023;
  bf16* outp = (f == 0) ? xrg : (f == 1) ? xwa : (f == 2) ? xk : xv;
  int ocol = c0 + fr;
  int orow0 = m0 + (wv << 5) + (fq << 2);
#define WRA(accv, mf, nt) { int cc = ocol + ((nt) << 4); \
    float ta = tmaa[(f << 10) + cc]; \
    _Pragma("unroll") for (int r = 0; r < 4; r++) { \
      int row = orow0 + ((mf) << 4) + r; \
      int t = row & (T_ - 1); \
      long xo = (long)row * C_ + cc; \
      float xb = x[xo]; \
      float xq = (t > 0) ? x[xo - C_] : 0.0f; \
      outp[xo] = f2bf(fmaf(xq - xb, ta + accv[r], xb)); } }
  WRA(a00, 0, 0) WRA(a01, 0, 1) WRA(a02, 0, 2) WRA(a03, 0, 3)
  WRA(a10, 1, 0) WRA(a11, 1, 1) WRA(a12, 1, 2) WRA(a13, 1, 3)
#undef WRA
}

// ---------------- K5: fuse2-lite (pure elementwise; dots via GEMM) ----------
// d2[m][j*1024+c] = {wd, ad, mad, kkd, mkd} fp32 from the w2e5 GEMM.
__global__ __launch_bounds__(256) void fuse2_kernel(
    const float* __restrict__ kraw, const float* __restrict__ d2,
    const float* __restrict__ tdec, const float* __restrict__ taa,
    const float* __restrict__ tma, const float* __restrict__ tmk,
    float* __restrict__ ew, float* __restrict__ kfin,
    float* __restrict__ kkn, float* __restrict__ bbo) {
  int m = blockIdx.x, tid = threadIdx.x;
  int c4 = tid << 2;
  const float* dp = d2 + (long)m * 5120;
  float4 wd4 = *(const float4*)(dp + c4);
  float4 ad4 = *(const float4*)(dp + 1024 + c4);
  float4 mad4 = *(const float4*)(dp + 2048 + c4);
  float4 kd4 = *(const float4*)(dp + 3072 + c4);
  float4 mkd4 = *(const float4*)(dp + 4096 + c4);
  float4 kraw4 = *(const float4*)(kraw + (long)m * C_ + c4);
  float4 tdec4 = *(const float4*)(tdec + c4);
  float4 taa4 = *(const float4*)(taa + c4);
  float4 tma4 = *(const float4*)(tma + c4);
  float4 tmk4 = *(const float4*)(tmk + c4);
  float wd[4] = {wd4.x, wd4.y, wd4.z, wd4.w};
  float ad[4] = {ad4.x, ad4.y, ad4.z, ad4.w};
  float mad[4] = {mad4.x, mad4.y, mad4.z, mad4.w};
  float kd[4] = {kd4.x, kd4.y, kd4.z, kd4.w};
  float mkd[4] = {mkd4.x, mkd4.y, mkd4.z, mkd4.w};
  float krw[4] = {kraw4.x, kraw4.y, kraw4.z, kraw4.w};
  float td[4] = {tdec4.x, tdec4.y, tdec4.z, tdec4.w};
  float ta[4] = {taa4.x, taa4.y, taa4.z, taa4.w};
  float tm[4] = {tma4.x, tma4.y, tma4.z, tma4.w};
  float tk[4] = {tmk4.x, tmk4.y, tmk4.z, tmk4.w};
  float kkp[4], av[4], wvv[4], kr[4], mkv[4];
  float sumsq = 0.f;
#pragma unroll
  for (int j = 0; j < 4; j++) {
    float w = -softplusf_(-(td[j] + wd[j])) - 0.5f;
    wvv[j] = w;
    float kkpre = krw[j] + kd[j];
    kkp[j] = kkpre;
    sumsq += kkpre * kkpre;
    float a = sigmoidf_(ta[j] + ad[j]);
    av[j] = a;
    float ma = sigmoidf_(tm[j] + mad[j]);
    float mk = sigmoidf_(tk[j] + mkd[j]);
    mkv[j] = mk;
    kr[j] = krw[j] * (ma + a * (1.f - ma));
  }
  sumsq += __shfl_xor(sumsq, 1);
  sumsq += __shfl_xor(sumsq, 2);
  sumsq += __shfl_xor(sumsq, 4);
  sumsq += __shfl_xor(sumsq, 8);
  float rn = 1.0f / fmaxf(sqrtf(sumsq), 1e-12f);
  float4 kknv, bbov, eww, kfv;
  float* kknp = (float*)&kknv;
  float* bbop = (float*)&bbov;
  float* ewp = (float*)&eww;
  float* kfp = (float*)&kfv;
#pragma unroll
  for (int j = 0; j < 4; j++) {
    float kkx = kkp[j] * rn;
    kknp[j] = kkx;
    bbop[j] = -kkx * av[j];
    ewp[j] = expf(wvv[j]);
    kfp[j] = kr[j] * expf(wvv[j] * mkv[j]);
  }
  long off4 = (long)m * C_ + c4;
  *(float4*)(kkn + off4) = kknv;
  *(float4*)(bbo + off4) = bbov;
  *(float4*)(ew + off4) = eww;
  *(float4*)(kfin + off4) = kfv;
}

// ---------------- K6: RWKV-7 scan, 128 blocks x 256 threads -----------------
// R3 structure (dbuf LDS, 3-set rotating register pipeline, sched_barrier) +
// R7 y-pipeline (qsum16x2 overlaps token t's sab chain with t-1's y chain).
// ~300 cyc/token floor; resisted packing/scheduling/interleave changes.
#define SCHUNK 16
#define NCHUNK (T_ / SCHUNK)
__global__ __launch_bounds__(256, 1) void scan_kernel(
    const float* __restrict__ rB, const float* __restrict__ ewB,
    const float* __restrict__ kB, const float* __restrict__ vB,
    const float* __restrict__ kkB, const float* __restrict__ bbB,
    float* __restrict__ yB) {
  __shared__ __align__(16) float lds[2][6][SCHUNK * 64];
  int bid = blockIdx.x;          // 0..127
  int bh = bid >> 2, rg = bid & 3;
  int b = bh >> 4, h = bh & 15;
  int tid = threadIdx.x;
  int wave = tid >> 6, lane = tid & 63;
  int g = lane >> 4, q = lane & 15;
  int row = (rg << 4) + (wave << 2) + g;
  int kq = q << 2;
  const long base = ((long)b * T_) * C_ + (h << 6);
  const float* s0 = kkB + base;
  const float* s1 = ewB + base;
  const float* s2 = kB + base;
  const float* s3 = bbB + base;
  const float* s4 = rB + base;
  const float* s5 = vB + base;
  int stok = tid >> 4;
  int spc = (tid & 15) << 2;
  int lo = (stok << 6) + spc;
  float4 rb0, rb1, rb2, rb3, rb4, rb5;
  auto loadc = [&](int c) {
    long go = (long)((c << 4) + stok) * C_ + spc;
    rb0 = *(const float4*)(s0 + go);
    rb1 = *(const float4*)(s1 + go);
    rb2 = *(const float4*)(s2 + go);
    rb3 = *(const float4*)(s3 + go);
    rb4 = *(const float4*)(s4 + go);
    rb5 = *(const float4*)(s5 + go);
  };
  auto stage = [&](int buf) {
    *(float4*)&lds[buf][0][lo] = rb0;
    *(float4*)&lds[buf][1][lo] = rb1;
    *(float4*)&lds[buf][2][lo] = rb2;
    *(float4*)&lds[buf][3][lo] = rb3;
    *(float4*)&lds[buf][4][lo] = rb4;
    *(float4*)&lds[buf][5][lo] = rb5;
  };
  float S0 = 0.f, S1 = 0.f, S2 = 0.f, S3 = 0.f;
  float ypv = 0.f;
  float4 Q0kk, Q0ew, Q0k, Q0bb, Q0r; float Q0v;
  float4 Q1kk, Q1ew, Q1k, Q1bb, Q1r; float Q1v;
  float4 Q2kk, Q2ew, Q2k, Q2bb, Q2r; float Q2v;

#define PF(i, tt) { int tb_ = ((tt) << 6); \
    Q##i##kk = *(const float4*)&lds[cur][0][tb_ + kq]; \
    Q##i##ew = *(const float4*)&lds[cur][1][tb_ + kq]; \
    Q##i##k  = *(const float4*)&lds[cur][2][tb_ + kq]; \
    Q##i##bb = *(const float4*)&lds[cur][3][tb_ + kq]; \
    Q##i##r  = *(const float4*)&lds[cur][4][tb_ + kq]; \
    Q##i##v  = lds[cur][5][tb_ + row]; }
#define SBAR __builtin_amdgcn_sched_barrier(0x7)
#define ST(i, gtok, FIRSTT) { \
    float p_ = fmaf(S1, Q##i##kk.y, S0 * Q##i##kk.x) + \
               fmaf(S3, Q##i##kk.w, S2 * Q##i##kk.z); \
    float yo_ = ypv; \
    qsum16x2(p_, yo_); \
    if (q == 0 && !((FIRSTT) && c == 0)) \
      yB[base + (long)((gtok) - 1) * C_ + row] = yo_; \
    float n0 = fmaf(S0, Q##i##ew.x, Q##i##v * Q##i##k.x); \
    float n1 = fmaf(S1, Q##i##ew.y, Q##i##v * Q##i##k.y); \
    float n2 = fmaf(S2, Q##i##ew.z, Q##i##v * Q##i##k.z); \
    float n3 = fmaf(S3, Q##i##ew.w, Q##i##v * Q##i##k.w); \
    S0 = fmaf(p_, Q##i##bb.x, n0); \
    S1 = fmaf(p_, Q##i##bb.y, n1); \
    S2 = fmaf(p_, Q##i##bb.z, n2); \
    S3 = fmaf(p_, Q##i##bb.w, n3); \
    ypv = fmaf(S1, Q##i##r.y, S0 * Q##i##r.x) + \
          fmaf(S3, Q##i##r.w, S2 * Q##i##r.z); }

  loadc(0);
  stage(0);
  loadc(1);
  __syncthreads();
  int cur = 0;
  for (int c = 0; c < NCHUNK; c++) {
    int t0 = c << 4;
    PF(0, 0); PF(1, 1);
    if (c + 1 < NCHUNK) stage(cur ^ 1);
    if (c + 2 < NCHUNK) loadc(c + 2);
    SBAR;
    PF(2, 2);  SBAR; ST(0, t0 + 0, true);
    PF(0, 3);  SBAR; ST(1, t0 + 1, false);
    PF(1, 4);  SBAR; ST(2, t0 + 2, false);
    PF(2, 5);  SBAR; ST(0, t0 + 3, false);
    PF(0, 6);  SBAR; ST(1, t0 + 4, false);
    PF(1, 7);  SBAR; ST(2, t0 + 5, false);
    PF(2, 8);  SBAR; ST(0, t0 + 6, false);
    PF(0, 9);  SBAR; ST(1, t0 + 7, false);
    PF(1, 10); SBAR; ST(2, t0 + 8, false);
    PF(2, 11); SBAR; ST(0, t0 + 9, false);
    PF(0, 12); SBAR; ST(1, t0 + 10, false);
    PF(1, 13); SBAR; ST(2, t0 + 11, false);
    PF(2, 14); SBAR; ST(0, t0 + 12, false);
    PF(0, 15); SBAR; ST(1, t0 + 13, false);
    ST(2, t0 + 14, false);
    ST(0, t0 + 15, false);
    __syncthreads();
    cur ^= 1;
  }
  {
    float yo = qsum16(ypv);
    if (q == 0) yB[base + (long)(T_ - 1) * C_ + row] = yo;
  }
#undef PF
#undef SBAR
#undef ST
}

// ---------------- K7: GroupNorm + bonus + gate (bf16 out) -------------------
__global__ __launch_bounds__(256) void gnout_kernel(
    const float* __restrict__ y, const float* __restrict__ r,
    const float* __restrict__ kf, const float* __restrict__ v,
    const float* __restrict__ g,
    const float* __restrict__ lnw, const float* __restrict__ lnb,
    const float* __restrict__ fa, bf16* __restrict__ z) {
  int tid = threadIdx.x;
  int w = tid >> 6, lane = tid & 63;
  int gi = (blockIdx.x << 2) + w;
  int h = gi & 15, mt = gi >> 4;
  long off = (long)mt * C_ + (h << 6) + lane;
  float yv = y[off];
  float s = yv;
  s += __shfl_xor(s, 1); s += __shfl_xor(s, 2); s += __shfl_xor(s, 4);
  s += __shfl_xor(s, 8); s += __shfl_xor(s, 16); s += __shfl_xor(s, 32);
  float mu = s * (1.0f / 64.0f);
  float d = yv - mu;
  float s2 = d * d;
  s2 += __shfl_xor(s2, 1); s2 += __shfl_xor(s2, 2); s2 += __shfl_xor(s2, 4);
  s2 += __shfl_xor(s2, 8); s2 += __shfl_xor(s2, 16); s2 += __shfl_xor(s2, 32);
  float var = s2 * (1.0f / 64.0f);
  int hc = (h << 6) + lane;
  float dot = r[off] * kf[off] * fa[hc];
  dot += __shfl_xor(dot, 1); dot += __shfl_xor(dot, 2); dot += __shfl_xor(dot, 4);
  dot += __shfl_xor(dot, 8); dot += __shfl_xor(dot, 16); dot += __shfl_xor(dot, 32);
  float yn = d * rsqrtf(var + 0.00064f) * lnw[hc] + lnb[hc];
  z[off] = f2bf((yn + dot * v[off]) * g[off]);
}

extern "C" void kernel_launch(void* const* d_in, const int* in_sizes, int n_in,
                              void* d_out, int out_size, void* d_ws, size_t ws_size,
                              hipStream_t stream) {
  const float* x = (const float*)d_in[0];
  const float* tmx = (const float*)d_in[1];
  const float* tmaa = (const float*)d_in[2];
  const float* tmw1 = (const float*)d_in[3];
  const float* tmw2 = (const float*)d_in[4];
  const float* tdec = (const float*)d_in[5];
  const float* tdw1 = (const float*)d_in[6];
  const float* tdw2 = (const float*)d_in[7];
  const float* taa5 = (const float*)d_in[8];
  const float* taw1 = (const float*)d_in[9];
  const float* taw2 = (const float*)d_in[10];
  const float* tkw1 = (const float*)d_in[11];
  const float* tkw2 = (const float*)d_in[12];
  const float* gw1 = (const float*)d_in[13];
  const float* gw2 = (const float*)d_in[14];
  const float* tmia = (const float*)d_in[15];
  const float* maw1 = (const float*)d_in[16];
  const float* maw2 = (const float*)d_in[17];
  const float* tmik = (const float*)d_in[18];
  const float* mkw1 = (const float*)d_in[19];
  const float* mkw2 = (const float*)d_in[20];
  const float* wrec = (const float*)d_in[21];
  const float* wkey = (const float*)d_in[22];
  const float* wval = (const float*)d_in[23];
  const float* wout = (const float*)d_in[24];
  const float* lnw = (const float*)d_in[25];
  const float* lnb = (const float*)d_in[26];
  const float* faaa = (const float*)d_in[27];

  const long MT = 2048, CC = 1024;
  char* base = (char*)d_ws;
  float* y = (float*)base;     base += MT * CC * 4;
  bf16* xrgb = (bf16*)base;    base += MT * CC * 2;   // ┐ kfin overlays (8MB)
  bf16* xwab = (bf16*)base;    base += MT * CC * 2;   // ┘
  bf16* xkb = (bf16*)base;     base += MT * CC * 2;   // ┐ kkn overlays (8MB)
  bf16* xvb = (bf16*)base;     base += MT * CC * 2;   // ┘
  float* rr = (float*)base;    base += MT * CC * 4;
  float* kraw = (float*)base;  base += MT * CC * 4;   // also ew
  float* vv = (float*)base;    base += MT * CC * 4;
  float* gg = (float*)base;    base += MT * CC * 4;
  float* bbo = (float*)base;   base += MT * CC * 4;
  bf16* g1b = (bf16*)base;     base += MT * 128 * 2;
  bf16* out12b = (bf16*)base;  base += MT * 128 * 2;  // [w1|a1|ma1|kk1|mk1]
  bf16* zb = (bf16*)base;      base += MT * CC * 2;
  bf16* mixb = (bf16*)base;    base += MT * 128 * 2;
  float* d2 = (float*)base;    base += MT * 5120L * 4; // fuse2 dots (fp32)
  bf16* tmw1b = (bf16*)base;   base += 128 * CC * 2;
  bf16* wrecb = (bf16*)base;   base += CC * CC * 2;
  bf16* gw1b = (bf16*)base;    base += 128 * CC * 2;
  bf16* gw2b = (bf16*)base;    base += CC * 128 * 2;
  bf16* wkeyb = (bf16*)base;   base += CC * CC * 2;
  bf16* wvalb = (bf16*)base;   base += CC * CC * 2;
  bf16* woutb = (bf16*)base;   base += CC * CC * 2;
  bf16* wskb = (bf16*)base;    base += 32 * CC * 2;
  bf16* wswab = (bf16*)base;   base += 96 * CC * 2;
  bf16* tmw2e = (bf16*)base;   base += 4096L * 128 * 2;
  bf16* w2e5b = (bf16*)base;   base += 5120L * 128 * 2;
  // aliases (dead-buffer reuse, verified non-overlapping in time):
  float* ew = kraw;            // fuse2 reads kraw then writes ew at same offs
  float* kfin = (float*)xrgb;  // xrg/xwa bf16 dead before fuse2
  float* kkn = (float*)xkb;    // xk/xv bf16 dead before fuse2

  cvt_all_kernel<<<5760, 256, 0, stream>>>(
      tmw1, wrec, gw1, gw2, wkey, wval, wout,
      tmw1b, wrecb, gw1b, gw2b, wkeyb, wvalb, woutb,
      tkw1, mkw1, tdw1, taw1, maw1, wskb, wswab,
      tmw2, tdw2, tkw2, taw2, maw2, mkw2,
      tmw2e, w2e5b);

  // mix GEMM with fused token-shift A-staging (bf16 out)
  gemm_mix_kernel<<<dim3(2, 16), 256, 0, stream>>>(x, tmx, tmw1b, mixb);
  // deltas GEMM with fused mix-apply epilogue -> xrg/xwa/xk/xv
  gemm_mixapply_kernel<<<dim3(64, 16), 256, 0, stream>>>(
      mixb, tmw2e, x, tmaa, xrgb, xwab, xkb, xvb);
  // 6 independent K=1024 GEMMs, one launch; z=3/z=5 write slices of out12b
  {
    GemmBatch gb = {};
    gb.A[0] = xrgb; gb.W[0] = wrecb; gb.Cf[0] = rr;      gb.Cb[0] = nullptr; gb.N[0] = 1024; gb.actN[0] = 0;   gb.ldc[0] = 1024; gb.coff[0] = 0;
    gb.A[1] = xrgb; gb.W[1] = gw1b;  gb.Cf[1] = nullptr; gb.Cb[1] = g1b;     gb.N[1] = 128;  gb.actN[1] = 128; gb.ldc[1] = 128;  gb.coff[1] = 0;
    gb.A[2] = xkb;  gb.W[2] = wkeyb; gb.Cf[2] = kraw;    gb.Cb[2] = nullptr; gb.N[2] = 1024; gb.actN[2] = 0;   gb.ldc[2] = 1024; gb.coff[2] = 0;
    gb.A[3] = xkb;  gb.W[3] = wskb;  gb.Cf[3] = nullptr; gb.Cb[3] = out12b;  gb.N[3] = 32;   gb.actN[3] = 16;  gb.ldc[3] = 128;  gb.coff[3] = 96;
    gb.A[4] = xvb;  gb.W[4] = wvalb; gb.Cf[4] = vv;      gb.Cb[4] = nullptr; gb.N[4] = 1024; gb.actN[4] = 0;   gb.ldc[4] = 1024; gb.coff[4] = 0;
    gb.A[5] = xwab; gb.W[5] = wswab; gb.Cf[5] = nullptr; gb.Cb[5] = out12b;  gb.N[5] = 96;   gb.actN[5] = 64;  gb.ldc[5] = 128;  gb.coff[5] = 0;
    gemm_batch_kernel<<<dim3(16, 16, 6), 256, 0, stream>>>(gb, 1024);
  }
  // batch2 (K=128): gg GEMM + fuse2-dots GEMM (d2 = out12b x w2e5^T, fp32)
  {
    GemmBatch gb = {};
    gb.A[0] = g1b;    gb.W[0] = gw2b;  gb.Cf[0] = gg; gb.Cb[0] = nullptr; gb.N[0] = 1024; gb.actN[0] = 0; gb.ldc[0] = 1024; gb.coff[0] = 0;
    gb.A[1] = out12b; gb.W[1] = w2e5b; gb.Cf[1] = d2; gb.Cb[1] = nullptr; gb.N[1] = 5120; gb.actN[1] = 0; gb.ldc[1] = 5120; gb.coff[1] = 0;
    gemm_batch_kernel<<<dim3(80, 16, 2), 256, 0, stream>>>(gb, 128);
  }
  fuse2_kernel<<<2048, 256, 0, stream>>>(kraw, d2, tdec, taa5, tmia, tmik,
                                         ew, kfin, kkn, bbo);
  scan_kernel<<<128, 256, 0, stream>>>(rr, ew, kfin, vv, kkn, bbo, y);
  gnout_kernel<<<8192, 256, 0, stream>>>(y, rr, kfin, vv, gg, lnw, lnb, faaa, zb);
  // output GEMM: (2048x1024)x(1024x1024)^T
  {
    GemmBatch gb = {};
    gb.A[0] = zb; gb.W[0] = woutb; gb.Cf[0] = (float*)d_out; gb.Cb[0] = nullptr;
    gb.N[0] = 1024; gb.actN[0] = 0; gb.ldc[0] = 1024; gb.coff[0] = 0;
    gemm_batch_kernel<<<dim3(16, 16, 1), 256, 0, stream>>>(gb, 1024);
  }
}